// Round 6
// baseline (11910.155 us; speedup 1.0000x reference)
//
#include <hip/hip_runtime.h>
#include <hip/hip_bf16.h>
#include <math.h>

#define GG 256
#define NP 24
#define LL 3
#define CC 256
#define NN (GG*NP)   // 6144 nodes

typedef __hip_bfloat16 bf;

__device__ __forceinline__ float b2f(bf x) { return __bfloat162float(x); }

// Per-input dual-dtype load. f32: nonzero = fp32, 0 = bf16.
__device__ __forceinline__ float ldf(const void* p, long i, int f32) {
    return f32 ? ((const float*)p)[i] : b2f(((const bf*)p)[i]);
}

struct Ptrs { const void* p[42]; int cnt[42]; };

// ---------------------------------------------------------------------------
// Per-input dtype probe (validated R5: selects fp32 path, matching hard-coded
// R4 bit-exactly). flags[i]: 1 = fp32, 0 = bf16. flags[42]: 1 = ints int64.
// ---------------------------------------------------------------------------
__global__ void detect_k(Ptrs a, const unsigned int* __restrict__ at, int* flags) {
    int i = threadIdx.x;
    if (i < 42) {
        const unsigned int* u = (const unsigned int*)a.p[i];
        int half_u32 = a.cnt[i] / 2;
        int nS = half_u32 < 64 ? half_u32 : 64;
        int band = 0, nz = 0;
        for (int k = 0; k < nS; ++k) {
            unsigned w = u[k];
            if (w) ++nz;
            unsigned mid = (w >> 7) & 0xFF;
            if (mid >= 96 && mid <= 128) ++band;
        }
        flags[i] = (nz == 0) ? 2 : ((band * 4 >= nS * 3) ? 0 : 1);
    }
    __syncthreads();
    if (i < 42 && flags[i] == 2) {
        int c4 = flags[4];                 // node_align_W: never all-zero
        flags[i] = (c4 == 2) ? 1 : c4;
    }
    if (i == 63) {
        int i64 = 1;
        for (int k = 0; k < 256; ++k)
            if (at[2 * k + 1] != 0u) { i64 = 0; break; }
        flags[42] = i64;
    }
}

// Diagnostic signal (fp32 now): fill first n outputs with a constant.
__global__ void signal_k(float* out, int n, float val) {
    int i = blockIdx.x * 256 + threadIdx.x;
    if (i < n) out[i] = val;
}

// ---------------------------------------------------------------------------
// A = [type_emb[atom_types] | time_emb]  (N x 512, fp32)
// ---------------------------------------------------------------------------
__global__ void build_A(const void* __restrict__ t, const void* __restrict__ type_emb,
                        const unsigned int* __restrict__ atoms,
                        float* __restrict__ A, const int* __restrict__ flags) {
    int ft = flags[0], fe = flags[3], i64 = flags[42];
    int idx = blockIdx.x * 256 + threadIdx.x;
    if (idx >= NN * 512) return;
    int n = idx >> 9;
    int k = idx & 511;
    if (k < 256) {
        int a = i64 ? (int)atoms[2 * n] : (int)atoms[n];
        A[idx] = ldf(type_emb, (long)a * CC + k, fe);
    } else {
        int d = k - 256;
        int g = n / NP;
        float tv = ldf(t, g, ft);
        int dd = (d < 128) ? d : d - 128;
        float tf = expf(dd * (-9.210340371976184f / 127.0f));
        float ang = tv * tf;
        A[idx] = (d < 128) ? sinf(ang) : cosf(ang);
    }
}

// ---------------------------------------------------------------------------
// NAIVE GEMM: one thread per output. C = epi(A@W + bias) (+res). fp32 out.
// ---------------------------------------------------------------------------
__global__ void gemm_naive(const float* __restrict__ A, const void* __restrict__ W,
                           long woff, const void* __restrict__ bias, long boff,
                           const float* __restrict__ res, float* __restrict__ Cf,
                           int M, int K, int Nc, int act,
                           int wi, int bi, const int* __restrict__ flags) {
    long idx = (long)blockIdx.x * 256 + threadIdx.x;
    if (idx >= (long)M * Nc) return;
    int m = (int)(idx / Nc), n = (int)(idx % Nc);
    int fw = flags[wi];
    float v = 0.f;
    for (int k = 0; k < K; ++k)
        v += A[(long)m * K + k] * ldf(W, woff + (long)k * Nc + n, fw);
    if (bias) v += ldf(bias, boff + n, flags[bi]);
    if (act == 1) v = fmaxf(v, 0.f);
    else if (act == 2) v = v / (1.f + expf(-v));
    if (res) v += res[(long)m * Nc + n];
    Cf[(long)m * Nc + n] = v;
}

// ---------------------------------------------------------------------------
// NAIVE GINEConv: one thread per (dst node, channel).
// ---------------------------------------------------------------------------
__global__ void gine_naive(const float* __restrict__ x, const void* __restrict__ frac,
                           const void* __restrict__ lattice, const void* __restrict__ geW,
                           const void* __restrict__ geb, float* __restrict__ z,
                           int l, const int* __restrict__ flags) {
    int idx = blockIdx.x * 256 + threadIdx.x;
    if (idx >= NN * CC) return;
    int ff = flags[1], fl2 = flags[2], fw = flags[6], fb = flags[7];
    int n = idx >> 8;
    int c = idx & 255;
    int g = n / NP;
    int jj = n % NP;
    long loff = (long)l * 69 * CC;
    float aggr = 0.f;
    for (int i = 0; i < NP; ++i) {
        float e = ldf(geb, (long)l * CC + c, fb);
        for (int d = 0; d < 3; ++d) {
            float fd = ldf(frac, (long)(g * NP + jj) * 3 + d, ff)
                     - ldf(frac, (long)(g * NP + i) * 3 + d, ff);
            fd -= floorf(fd);
            for (int f = 0; f < 10; ++f) {
                float ang = 6.283185307179586f * (float)f * fd;
                int r = d * 10 + f;
                e += sinf(ang) * ldf(geW, loff + (long)r * CC + c, fw);
                e += cosf(ang) * ldf(geW, loff + (long)(30 + r) * CC + c, fw);
            }
        }
        for (int q = 0; q < 9; ++q)
            e += ldf(lattice, (long)g * 9 + q, fl2) * ldf(geW, loff + (long)(60 + q) * CC + c, fw);
        float msg = x[(long)(g * NP + i) * CC + c] + e;
        aggr += fmaxf(msg, 0.f);
    }
    z[(long)n * CC + c] = x[(long)n * CC + c] + aggr;
}

// ---------------------------------------------------------------------------
__global__ void bn_stats_naive(const float* __restrict__ in, float* __restrict__ stats) {
    int c = threadIdx.x;
    float s = 0.f, q = 0.f;
    for (int r = 0; r < NN; ++r) {
        float v = in[(long)r * CC + c];
        s += v; q += v * v;
    }
    float m = s / (float)NN;
    float var = q / (float)NN - m * m;
    stats[c] = m;
    stats[256 + c] = rsqrtf(var + 1e-5f);
}
__global__ void bn_apply(const float* __restrict__ in, const float* __restrict__ stats,
                         const void* __restrict__ gma, const void* __restrict__ bta,
                         long off, const float* __restrict__ add, float* __restrict__ out,
                         int gi, int bi, const int* __restrict__ flags) {
    int fg = flags[gi], fb = flags[bi];
    long idx = (long)blockIdx.x * 256 + threadIdx.x;
    int c = (int)(idx & 255);
    float v = (in[idx] - stats[c]) * stats[256 + c] * ldf(gma, off + c, fg)
            + ldf(bta, off + c, fb);
    if (add) v += add[idx];
    out[idx] = v;
}

// ---------------------------------------------------------------------------
// NAIVE attention: one thread per (graph, head, query-row).
// ---------------------------------------------------------------------------
__global__ void attn_naive(const float* __restrict__ qkv, float* __restrict__ o) {
    int idx = blockIdx.x * 256 + threadIdx.x;
    if (idx >= GG * 4 * NP) return;
    int g = idx / (4 * NP);
    int rem = idx % (4 * NP);
    int h = rem / NP;
    int row = rem % NP;
    const float* qp = qkv + (long)(g * NP + row) * 768 + h * 64;
    float sc[NP];
    float mx = -1e30f;
    for (int j = 0; j < NP; ++j) {
        const float* kp = qkv + (long)(g * NP + j) * 768 + 256 + h * 64;
        float s = 0.f;
        for (int d = 0; d < 64; ++d) s += qp[d] * kp[d];
        s *= 0.125f;
        sc[j] = s;
        mx = fmaxf(mx, s);
    }
    float sum = 0.f;
    for (int j = 0; j < NP; ++j) { float p = expf(sc[j] - mx); sc[j] = p; sum += p; }
    float inv = 1.f / sum;
    float* op = o + (long)(g * NP + row) * CC + h * 64;
    for (int d = 0; d < 64; ++d) {
        float a = 0.f;
        for (int j = 0; j < NP; ++j)
            a += sc[j] * qkv[(long)(g * NP + j) * 768 + 512 + h * 64 + d];
        op[d] = a * inv;
    }
}

// ---------------------------------------------------------------------------
__global__ void ln_naive(const float* __restrict__ x, const void* __restrict__ gma,
                         const void* __restrict__ bta, float* __restrict__ out,
                         const int* __restrict__ flags) {
    int n = blockIdx.x * 256 + threadIdx.x;
    if (n >= NN) return;
    int fg = flags[26], fb = flags[27];
    const float* xp = x + (long)n * CC;
    float m = 0.f;
    for (int c = 0; c < CC; ++c) m += xp[c];
    m *= (1.f / 256.f);
    float var = 0.f;
    for (int c = 0; c < CC; ++c) { float dv = xp[c] - m; var += dv * dv; }
    var *= (1.f / 256.f);
    float rs = rsqrtf(var + 1e-5f);
    float* op = out + (long)n * CC;
    for (int c = 0; c < CC; ++c)
        op[c] = (xp[c] - m) * rs * ldf(gma, c, fg) + ldf(bta, c, fb);
}

__global__ void pool_kernel(const float* __restrict__ hn, float* __restrict__ gf) {
    int g = blockIdx.x, c = threadIdx.x;
    float s = 0.f;
    for (int j = 0; j < NP; ++j) s += hn[(long)(g * NP + j) * CC + c];
    gf[g * CC + c] = s * (1.f / 24.f);
}

// ---------------------------------------------------------------------------
static void gemm(hipStream_t st, const int* flags, const float* A,
                 const void* W, long woff, int wi, const void* bias, long boff, int bi,
                 const float* res, float* Cf, int M, int K, int Nc, int act) {
    long total = (long)M * Nc;
    int grid = (int)((total + 255) / 256);
    gemm_naive<<<grid, 256, 0, st>>>(A, W, woff, bias, boff, res, Cf,
                                     M, K, Nc, act, wi, bi < 0 ? 0 : bi, flags);
}

static void run_bn(hipStream_t st, const int* flags, const float* in, float* stats,
                   const void* g_, const void* b_, long off, int gi, int bi,
                   const float* add, float* out) {
    bn_stats_naive<<<1, 256, 0, st>>>(in, stats);
    bn_apply<<<NN, 256, 0, st>>>(in, stats, g_, b_, off, add, out, gi, bi, flags);
}

extern "C" void kernel_launch(void* const* d_in, const int* in_sizes, int n_in,
                              void* d_out, int out_size, void* d_ws, size_t ws_size,
                              hipStream_t stream) {
    float* out = (float*)d_out;    // reference output dtype is float32
    int sigN = out_size < 256 ? out_size : 256;

    static const int EXP_SIZES[46] = {
        256, 18432, 2304, 25600, 131072, 256, 52992, 768, 196608, 768,
        196608, 768, 589824, 2304, 196608, 768, 393216, 1536, 393216, 768,
        768, 768, 768, 768, 768, 768, 256, 256, 32768, 128,
        12800, 100, 32768, 128, 8192, 64, 576, 32768, 128, 8192,
        64, 192, 6144, 6144, 147456, 147456 };
    if (n_in != 46) { signal_k<<<1, 256, 0, stream>>>(out, sigN, 3000.f + 8.f * n_in); return; }
    for (int i = 0; i < 46; ++i)
        if (in_sizes[i] != EXP_SIZES[i]) { signal_k<<<1, 256, 0, stream>>>(out, sigN, 512.f + 8.f * i); return; }
    if (out_size != NN * 100 + GG * 9 + NN * 3) { signal_k<<<1, 256, 0, stream>>>(out, sigN, 7777.f); return; }

    // ---- workspace ----
    char* base = (char*)d_ws;
    int* flags = (int*)base;                       // 256 B
    float* f32a = (float*)(base + 256);
    float* x  = f32a;                              // N*256
    float* s1 = x  + (size_t)NN * 256;             // N*256
    float* s2 = s1 + (size_t)NN * 256;             // N*256
    float* big = s2 + (size_t)NN * 256;            // N*768
    float* s3 = big + (size_t)NN * 512;            // alias of big's tail (lifetimes audited)
    float* stats = big + (size_t)NN * 768;         // 512
    float* gf  = stats + 512;                      // G*256
    float* l1b = gf + GG * 256;                    // G*128
    float* l2b = l1b + GG * 128;                   // G*64
    size_t REQ = 256 + ((size_t)NN * 1536 + 512 + GG * 448) * 4;
    if (ws_size < REQ) { signal_k<<<1, 256, 0, stream>>>(out, sigN, 9999.f); return; }

    Ptrs pa;
    for (int i = 0; i < 42; ++i) { pa.p[i] = d_in[i]; pa.cnt[i] = in_sizes[i]; }
    detect_k<<<1, 64, 0, stream>>>(pa, (const unsigned int*)d_in[42], flags);

    // x0 = concat(type_emb[atoms], time_emb) @ naW + nab
    build_A<<<(NN * 512 + 255) / 256, 256, 0, stream>>>(d_in[0], d_in[3],
        (const unsigned int*)d_in[42], big, flags);
    gemm(stream, flags, big, d_in[4], 0, 4, d_in[5], 0, 5, nullptr, x, NN, 512, 256, 0);

    for (int l = 0; l < LL; ++l) {
        gine_naive<<<(NN * CC + 255) / 256, 256, 0, stream>>>(
            x, d_in[1], d_in[2], d_in[6], d_in[7], s1, l, flags);
        gemm(stream, flags, s1, d_in[8],  (long)l * 65536, 8, d_in[9],  l * 256, 9, nullptr, s2, NN, 256, 256, 2);
        gemm(stream, flags, s2, d_in[10], (long)l * 65536, 10, d_in[11], l * 256, 11, x, s3, NN, 256, 256, 0);
        run_bn(stream, flags, s3, stats, d_in[20], d_in[21], l * 256, 20, 21, nullptr, s2);
        gemm(stream, flags, x, d_in[12], (long)l * 196608, 12, d_in[13], l * 768, 13, nullptr, big, NN, 256, 768, 0);
        attn_naive<<<(GG * 4 * NP + 255) / 256, 256, 0, stream>>>(big, s1);
        gemm(stream, flags, s1, d_in[14], (long)l * 65536, 14, d_in[15], l * 256, 15, x, s3, NN, 256, 256, 0);
        run_bn(stream, flags, s3, stats, d_in[22], d_in[23], l * 256, 22, 23, s2, s1);
        gemm(stream, flags, s1, d_in[16], (long)l * 131072, 16, d_in[17], l * 512, 17, nullptr, big, NN, 256, 512, 1);
        gemm(stream, flags, big, d_in[18], (long)l * 131072, 18, d_in[19], l * 256, 19, s1, s3, NN, 512, 256, 0);
        run_bn(stream, flags, s3, stats, d_in[24], d_in[25], l * 256, 24, 25, nullptr, x);
    }

    ln_naive<<<(NN + 255) / 256, 256, 0, stream>>>(x, d_in[26], d_in[27], s1, flags);
    pool_kernel<<<GG, 256, 0, stream>>>(s1, gf);

    // types_pred -> out[0 : N*100]
    gemm(stream, flags, s1, d_in[28], 0, 28, d_in[29], 0, 29, nullptr, s2, NN, 256, 128, 2);
    gemm(stream, flags, s2, d_in[30], 0, 30, d_in[31], 0, 31, nullptr, out, NN, 128, 100, 0);
    // lattice_pred -> out[N*100 : +G*9]
    gemm(stream, flags, gf,  d_in[32], 0, 32, d_in[33], 0, 33, nullptr, l1b, GG, 256, 128, 2);
    gemm(stream, flags, l1b, d_in[34], 0, 34, d_in[35], 0, 35, nullptr, l2b, GG, 128, 64, 2);
    gemm(stream, flags, l2b, d_in[36], 0, 36, nullptr, 0, -1, nullptr, out + (size_t)NN * 100, GG, 64, 9, 0);
    // frac_pred -> out[N*100+G*9 : ]
    gemm(stream, flags, s1, d_in[37], 0, 37, d_in[38], 0, 38, nullptr, s2, NN, 256, 128, 2);
    gemm(stream, flags, s2, d_in[39], 0, 39, d_in[40], 0, 40, nullptr, s3, NN, 128, 64, 2);
    gemm(stream, flags, s3, d_in[41], 0, 41, nullptr, 0, -1, nullptr, out + (size_t)NN * 100 + GG * 9, NN, 64, 3, 0);
}

// Round 7
// 2528.023 us; speedup vs baseline: 4.7113x; 4.7113x over previous
//
#include <hip/hip_runtime.h>
#include <hip/hip_bf16.h>
#include <math.h>

#define GG 256
#define NP 24
#define LL 3
#define CC 256
#define NN (GG*NP)   // 6144 nodes
#define HH 4
#define DH 64

// ---------------------------------------------------------------------------
// Int-width probe (atom_types int32 vs int64). flags[0]=1 -> int64.
// ---------------------------------------------------------------------------
__global__ void detect_int_k(const unsigned int* __restrict__ at, int* flags) {
    if (threadIdx.x == 0) {
        int i64 = 1;
        for (int k = 0; k < 256; ++k)
            if (at[2 * k + 1] != 0u) { i64 = 0; break; }
        flags[0] = i64;
    }
}

__global__ void signal_k(float* out, int n, float val) {
    int i = blockIdx.x * 256 + threadIdx.x;
    if (i < n) out[i] = val;
}

// ---------------------------------------------------------------------------
// A = [type_emb[atom_types] | time_emb]  (N x 512, fp32)
// ---------------------------------------------------------------------------
__global__ void build_A(const float* __restrict__ t, const float* __restrict__ type_emb,
                        const unsigned int* __restrict__ atoms,
                        float* __restrict__ A, const int* __restrict__ flags) {
    int i64 = flags[0];
    int idx = blockIdx.x * 256 + threadIdx.x;
    if (idx >= NN * 512) return;
    int n = idx >> 9;
    int k = idx & 511;
    if (k < 256) {
        int a = i64 ? (int)atoms[2 * n] : (int)atoms[n];
        A[idx] = type_emb[(long)a * CC + k];
    } else {
        int d = k - 256;
        int g = n / NP;
        float tv = t[g];
        int dd = (d < 128) ? d : d - 128;
        float tf = expf(dd * (-9.210340371976184f / 127.0f));
        float ang = tv * tf;
        A[idx] = (d < 128) ? sinf(ang) : cosf(ang);
    }
}

// ---------------------------------------------------------------------------
// Tiled GEMM: C[M,Nc] = epi(A[M,K] @ W[K,Nc] + bias) (+res). All fp32.
// 64x64 tile, 256 threads, 4x4 acc/thread. M%64==0, K%16==0, Nc arbitrary.
// act: 0 none, 1 relu, 2 silu.
// ---------------------------------------------------------------------------
__global__ __launch_bounds__(256) void gemm_k(
        const float* __restrict__ A, const float* __restrict__ W,
        const float* __restrict__ bias, const float* __restrict__ res,
        float* __restrict__ Cf, int M, int K, int Nc, int act) {
    __shared__ __align__(16) float As[16][64];
    __shared__ __align__(16) float Bs[16][64];
    int tid = threadIdx.x;
    int tx = tid & 15, ty = tid >> 4;
    int m0 = blockIdx.x * 64, n0 = blockIdx.y * 64;
    float acc[4][4] = {{0.f}};
    int am = tid >> 2;           // 0..63
    int ak = (tid & 3) << 2;     // 0,4,8,12
    int bk = tid >> 4;           // 0..15
    int bn = (tid & 15) << 2;    // 0..60

    for (int k0 = 0; k0 < K; k0 += 16) {
        float4 av = *(const float4*)(A + (long)(m0 + am) * K + k0 + ak);
        As[ak + 0][am] = av.x; As[ak + 1][am] = av.y;
        As[ak + 2][am] = av.z; As[ak + 3][am] = av.w;
#pragma unroll
        for (int u = 0; u < 4; ++u) {
            int n = n0 + bn + u;
            Bs[bk][bn + u] = (n < Nc) ? W[(long)(k0 + bk) * Nc + n] : 0.f;
        }
        __syncthreads();
#pragma unroll
        for (int k = 0; k < 16; ++k) {
            float4 a = *(const float4*)(&As[k][ty << 2]);
            float4 b = *(const float4*)(&Bs[k][tx << 2]);
            acc[0][0] += a.x * b.x; acc[0][1] += a.x * b.y; acc[0][2] += a.x * b.z; acc[0][3] += a.x * b.w;
            acc[1][0] += a.y * b.x; acc[1][1] += a.y * b.y; acc[1][2] += a.y * b.z; acc[1][3] += a.y * b.w;
            acc[2][0] += a.z * b.x; acc[2][1] += a.z * b.y; acc[2][2] += a.z * b.z; acc[2][3] += a.z * b.w;
            acc[3][0] += a.w * b.x; acc[3][1] += a.w * b.y; acc[3][2] += a.w * b.z; acc[3][3] += a.w * b.w;
        }
        __syncthreads();
    }
#pragma unroll
    for (int i = 0; i < 4; ++i) {
        int m = m0 + (ty << 2) + i;
#pragma unroll
        for (int j = 0; j < 4; ++j) {
            int n = n0 + (tx << 2) + j;
            if (n >= Nc) continue;
            float v = acc[i][j];
            if (bias) v += bias[n];
            if (act == 1) v = fmaxf(v, 0.f);
            else if (act == 2) v = v / (1.f + expf(-v));
            if (res) v += res[(long)m * Nc + n];
            Cf[(long)m * Nc + n] = v;
        }
    }
}

// ---------------------------------------------------------------------------
// Fused GINEConv. Block = (graph g, channel-half). 128 threads, one channel
// each. Edge weights (60 per channel) held in REGISTERS; per-src-row edge
// features built cooperatively in LDS and broadcast to all channels.
// Semantics == gine_naive (validated R6): z[j] = x[j] + sum_i relu(x[i]+e(i->j)).
// ---------------------------------------------------------------------------
__global__ __launch_bounds__(128) void gine_fused(
        const float* __restrict__ x, const float* __restrict__ frac,
        const float* __restrict__ lattice, const float* __restrict__ geW,
        const float* __restrict__ geb, float* __restrict__ z, int l) {
    __shared__ __align__(16) float er[24 * 60];   // eattr sin/cos for all dst j, fixed src i
    __shared__ float fr[24 * 3];
    int tid = threadIdx.x;
    int g = blockIdx.x >> 1;
    int half = blockIdx.x & 1;
    int c = half * 128 + tid;
    const float* Wg = geW + (long)l * 69 * CC;

    // 60 sin/cos weights for this channel -> registers
    float Wc[60];
#pragma unroll
    for (int k = 0; k < 60; ++k) Wc[k] = Wg[(long)k * CC + c];

    for (int idx = tid; idx < 72; idx += 128) fr[idx] = frac[g * 72 + idx];

    // per-graph lattice contribution (constant per channel) + bias
    float base = geb[(long)l * CC + c];
#pragma unroll
    for (int q = 0; q < 9; ++q)
        base += lattice[(long)g * 9 + q] * Wg[(long)(60 + q) * CC + c];

    float xi[24];
#pragma unroll
    for (int i = 0; i < 24; ++i) xi[i] = x[(long)(g * NP + i) * CC + c];
    float acc[24];
#pragma unroll
    for (int j = 0; j < 24; ++j) acc[j] = 0.f;

    for (int i = 0; i < 24; ++i) {
        __syncthreads();   // protect er from previous iteration's readers
        // build eattr rows for src i, all dst j: fd = (frac[j]-frac[i]) mod 1
        for (int item = tid; item < 720; item += 128) {
            int j = item / 30, r = item % 30;
            int d = r / 10, f = r % 10;
            float fd = fr[j * 3 + d] - fr[i * 3 + d];
            fd -= floorf(fd);
            float ang = 6.283185307179586f * (float)f * fd;
            er[j * 60 + r] = sinf(ang);
            er[j * 60 + 30 + r] = cosf(ang);
        }
        __syncthreads();
        float t0 = xi[i] + base;
#pragma unroll 4
        for (int j = 0; j < 24; ++j) {
            float v = t0;
            const float4* e4 = (const float4*)(er + j * 60);
#pragma unroll
            for (int k4 = 0; k4 < 15; ++k4) {
                float4 e = e4[k4];
                int kb = k4 * 4;
                v += e.x * Wc[kb + 0];
                v += e.y * Wc[kb + 1];
                v += e.z * Wc[kb + 2];
                v += e.w * Wc[kb + 3];
            }
            acc[j] += fmaxf(v, 0.f);
        }
    }
#pragma unroll
    for (int j = 0; j < 24; ++j)
        z[(long)(g * NP + j) * CC + c] = xi[j] + acc[j];
}

// ---------------------------------------------------------------------------
// BatchNorm, two-stage stats (96 blocks x 64 rows, then combine).
// ---------------------------------------------------------------------------
__global__ void bn_stats1(const float* __restrict__ in, float* __restrict__ part) {
    int c = threadIdx.x, b = blockIdx.x;
    float s = 0.f, q = 0.f;
    for (int r = 0; r < 64; ++r) {
        float v = in[(long)(b * 64 + r) * CC + c];
        s += v; q += v * v;
    }
    part[b * 512 + c] = s;
    part[b * 512 + 256 + c] = q;
}
__global__ void bn_stats2(const float* __restrict__ part, float* __restrict__ stats) {
    int c = threadIdx.x;
    float s = 0.f, q = 0.f;
    for (int b = 0; b < 96; ++b) { s += part[b * 512 + c]; q += part[b * 512 + 256 + c]; }
    float m = s / (float)NN;
    float var = q / (float)NN - m * m;
    stats[c] = m;
    stats[256 + c] = rsqrtf(var + 1e-5f);
}
__global__ void bn_apply(const float* __restrict__ in, const float* __restrict__ stats,
                         const float* __restrict__ gma, const float* __restrict__ bta,
                         const float* __restrict__ add, float* __restrict__ out) {
    long idx = (long)blockIdx.x * 256 + threadIdx.x;
    int c = (int)(idx & 255);
    float v = (in[idx] - stats[c]) * stats[256 + c] * gma[c] + bta[c];
    if (add) v += add[idx];
    out[idx] = v;
}

// ---------------------------------------------------------------------------
// Attention: one thread per (graph, head, query-row)  [validated R6]
// ---------------------------------------------------------------------------
__global__ void attn_naive(const float* __restrict__ qkv, float* __restrict__ o) {
    int idx = blockIdx.x * 256 + threadIdx.x;
    if (idx >= GG * HH * NP) return;
    int g = idx / (HH * NP);
    int rem = idx % (HH * NP);
    int h = rem / NP;
    int row = rem % NP;
    const float* qp = qkv + (long)(g * NP + row) * 768 + h * 64;
    float sc[NP];
    float mx = -1e30f;
    for (int j = 0; j < NP; ++j) {
        const float* kp = qkv + (long)(g * NP + j) * 768 + 256 + h * 64;
        float s = 0.f;
        for (int d = 0; d < 64; ++d) s += qp[d] * kp[d];
        s *= 0.125f;
        sc[j] = s;
        mx = fmaxf(mx, s);
    }
    float sum = 0.f;
    for (int j = 0; j < NP; ++j) { float p = expf(sc[j] - mx); sc[j] = p; sum += p; }
    float inv = 1.f / sum;
    float* op = o + (long)(g * NP + row) * CC + h * 64;
    for (int d = 0; d < 64; ++d) {
        float a = 0.f;
        for (int j = 0; j < NP; ++j)
            a += sc[j] * qkv[(long)(g * NP + j) * 768 + 512 + h * 64 + d];
        op[d] = a * inv;
    }
}

// ---------------------------------------------------------------------------
// LayerNorm, one block (256 threads) per node.
// ---------------------------------------------------------------------------
__global__ __launch_bounds__(256) void ln_kernel(const float* __restrict__ x,
        const float* __restrict__ gma, const float* __restrict__ bta,
        float* __restrict__ out) {
    __shared__ float red[256];
    int n = blockIdx.x, c = threadIdx.x;
    float v = x[(long)n * CC + c];
    red[c] = v;
    __syncthreads();
    for (int s = 128; s > 0; s >>= 1) { if (c < s) red[c] += red[c + s]; __syncthreads(); }
    float m = red[0] * (1.f / 256.f);
    __syncthreads();
    float dv = v - m;
    red[c] = dv * dv;
    __syncthreads();
    for (int s = 128; s > 0; s >>= 1) { if (c < s) red[c] += red[c + s]; __syncthreads(); }
    float var = red[0] * (1.f / 256.f);
    out[(long)n * CC + c] = dv * rsqrtf(var + 1e-5f) * gma[c] + bta[c];
}

__global__ void pool_kernel(const float* __restrict__ hn, float* __restrict__ gf) {
    int g = blockIdx.x, c = threadIdx.x;
    float s = 0.f;
    for (int j = 0; j < NP; ++j) s += hn[(long)(g * NP + j) * CC + c];
    gf[g * CC + c] = s * (1.f / 24.f);
}

// ---------------------------------------------------------------------------
static void gemm(hipStream_t st, const float* A, const float* W, const float* bias,
                 const float* res, float* Cf, int M, int K, int Nc, int act) {
    dim3 grid(M / 64, (Nc + 63) / 64);
    gemm_k<<<grid, 256, 0, st>>>(A, W, bias, res, Cf, M, K, Nc, act);
}

static void run_bn(hipStream_t st, const float* in, float* part, float* stats,
                   const float* g_, const float* b_, const float* add, float* out) {
    bn_stats1<<<96, 256, 0, st>>>(in, part);
    bn_stats2<<<1, 256, 0, st>>>(part, stats);
    bn_apply<<<NN, 256, 0, st>>>(in, stats, g_, b_, add, out);
}

extern "C" void kernel_launch(void* const* d_in, const int* in_sizes, int n_in,
                              void* d_out, int out_size, void* d_ws, size_t ws_size,
                              hipStream_t stream) {
    float* out = (float*)d_out;
    int sigN = out_size < 256 ? out_size : 256;

    static const int EXP_SIZES[46] = {
        256, 18432, 2304, 25600, 131072, 256, 52992, 768, 196608, 768,
        196608, 768, 589824, 2304, 196608, 768, 393216, 1536, 393216, 768,
        768, 768, 768, 768, 768, 768, 256, 256, 32768, 128,
        12800, 100, 32768, 128, 8192, 64, 576, 32768, 128, 8192,
        64, 192, 6144, 6144, 147456, 147456 };
    if (n_in != 46) { signal_k<<<1, 256, 0, stream>>>(out, sigN, 3000.f + 8.f * n_in); return; }
    for (int i = 0; i < 46; ++i)
        if (in_sizes[i] != EXP_SIZES[i]) { signal_k<<<1, 256, 0, stream>>>(out, sigN, 512.f + 8.f * i); return; }
    if (out_size != NN * 100 + GG * 9 + NN * 3) { signal_k<<<1, 256, 0, stream>>>(out, sigN, 7777.f); return; }

    // ---- workspace (same layout as validated R6) ----
    char* base = (char*)d_ws;
    int* flags = (int*)base;                       // 256 B
    float* f32a = (float*)(base + 256);
    float* x  = f32a;                              // N*256
    float* s1 = x  + (size_t)NN * 256;             // N*256
    float* s2 = s1 + (size_t)NN * 256;             // N*256
    float* big = s2 + (size_t)NN * 256;            // N*768
    float* s3 = big + (size_t)NN * 512;            // alias of big's tail (lifetimes audited R5/R6)
    float* part = big + (size_t)NN * 768;          // 96*512
    float* stats = part + 96 * 512;                // 512
    float* gf  = stats + 512;                      // G*256
    float* l1b = gf + GG * 256;                    // G*128
    float* l2b = l1b + GG * 128;                   // G*64
    size_t REQ = 256 + ((size_t)NN * 1536 + 96 * 512 + 512 + GG * 448) * 4;
    if (ws_size < REQ) { signal_k<<<1, 256, 0, stream>>>(out, sigN, 9999.f); return; }

    const float* t       = (const float*)d_in[0];
    const float* frac    = (const float*)d_in[1];
    const float* lattice = (const float*)d_in[2];
    const float* type_emb = (const float*)d_in[3];

    detect_int_k<<<1, 64, 0, stream>>>((const unsigned int*)d_in[42], flags);

    // x0 = concat(type_emb[atoms], time_emb) @ naW + nab
    build_A<<<(NN * 512 + 255) / 256, 256, 0, stream>>>(t, type_emb,
        (const unsigned int*)d_in[42], big, flags);
    gemm(stream, big, (const float*)d_in[4], (const float*)d_in[5], nullptr, x, NN, 512, 256, 0);

    for (int l = 0; l < LL; ++l) {
        // GINE: s1 = x + aggr
        gine_fused<<<GG * 2, 128, 0, stream>>>(x, frac, lattice,
            (const float*)d_in[6], (const float*)d_in[7], s1, l);
        // s2 = silu(s1@gW1+gb1); s3 = s2@gW2+gb2 + x; h1 = BN(s3) -> s2
        gemm(stream, s1, (const float*)d_in[8]  + (long)l * 65536, (const float*)d_in[9]  + l * 256, nullptr, s2, NN, 256, 256, 2);
        gemm(stream, s2, (const float*)d_in[10] + (long)l * 65536, (const float*)d_in[11] + l * 256, x, s3, NN, 256, 256, 0);
        run_bn(stream, s3, part, stats, (const float*)d_in[20] + l * 256, (const float*)d_in[21] + l * 256, nullptr, s2);
        // attention: qkv=big; o=s1; s3 = s1@aoW+aob + x; s1 = h1 + BN(s3)
        gemm(stream, x, (const float*)d_in[12] + (long)l * 196608, (const float*)d_in[13] + l * 768, nullptr, big, NN, 256, 768, 0);
        attn_naive<<<(GG * HH * NP + 255) / 256, 256, 0, stream>>>(big, s1);
        gemm(stream, s1, (const float*)d_in[14] + (long)l * 65536, (const float*)d_in[15] + l * 256, x, s3, NN, 256, 256, 0);
        run_bn(stream, s3, part, stats, (const float*)d_in[22] + l * 256, (const float*)d_in[23] + l * 256, s2, s1);
        // MLP: big = relu(s1@mW1+mb1); s3 = big@mW2+mb2 + s1; x = BN(s3)
        gemm(stream, s1, (const float*)d_in[16] + (long)l * 131072, (const float*)d_in[17] + l * 512, nullptr, big, NN, 256, 512, 1);
        gemm(stream, big, (const float*)d_in[18] + (long)l * 131072, (const float*)d_in[19] + l * 256, s1, s3, NN, 512, 256, 0);
        run_bn(stream, s3, part, stats, (const float*)d_in[24] + l * 256, (const float*)d_in[25] + l * 256, nullptr, x);
    }

    ln_kernel<<<NN, 256, 0, stream>>>(x, (const float*)d_in[26], (const float*)d_in[27], s1);
    pool_kernel<<<GG, 256, 0, stream>>>(s1, gf);

    // types_pred -> out[0 : N*100]
    gemm(stream, s1, (const float*)d_in[28], (const float*)d_in[29], nullptr, s2, NN, 256, 128, 2);
    gemm(stream, s2, (const float*)d_in[30], (const float*)d_in[31], nullptr, out, NN, 128, 100, 0);
    // lattice_pred -> out[N*100 : +G*9]
    gemm(stream, gf,  (const float*)d_in[32], (const float*)d_in[33], nullptr, l1b, GG, 256, 128, 2);
    gemm(stream, l1b, (const float*)d_in[34], (const float*)d_in[35], nullptr, l2b, GG, 128, 64, 2);
    gemm(stream, l2b, (const float*)d_in[36], nullptr, nullptr, out + (size_t)NN * 100, GG, 64, 9, 0);
    // frac_pred -> out[N*100+G*9 : ]
    gemm(stream, s1, (const float*)d_in[37], (const float*)d_in[38], nullptr, s2, NN, 256, 128, 2);
    gemm(stream, s2, (const float*)d_in[39], (const float*)d_in[40], nullptr, s3, NN, 128, 64, 2);
    gemm(stream, s3, (const float*)d_in[41], nullptr, nullptr, out + (size_t)NN * 100 + GG * 9, NN, 64, 3, 0);
}

// Round 8
// 1775.666 us; speedup vs baseline: 6.7074x; 1.4237x over previous
//
#include <hip/hip_runtime.h>
#include <hip/hip_bf16.h>
#include <math.h>

#define GG 256
#define NP 24
#define LL 3
#define CC 256
#define NN (GG*NP)   // 6144 nodes
#define HH 4
#define DH 64

// ---------------------------------------------------------------------------
// Int-width probe (atom_types int32 vs int64), parallel. flags[0]=1 -> int64.
// ---------------------------------------------------------------------------
__global__ void detect_int_k(const unsigned int* __restrict__ at, int* flags) {
    __shared__ int ok;
    if (threadIdx.x == 0) ok = 1;
    __syncthreads();
    if (at[2 * threadIdx.x + 1] != 0u) ok = 0;   // benign race
    __syncthreads();
    if (threadIdx.x == 0) flags[0] = ok;
}

__global__ void signal_k(float* out, int n, float val) {
    int i = blockIdx.x * 256 + threadIdx.x;
    if (i < n) out[i] = val;
}

// ---------------------------------------------------------------------------
// A = [type_emb[atom_types] | time_emb]  (N x 512, fp32)
// ---------------------------------------------------------------------------
__global__ void build_A(const float* __restrict__ t, const float* __restrict__ type_emb,
                        const unsigned int* __restrict__ atoms,
                        float* __restrict__ A, const int* __restrict__ flags) {
    int i64 = flags[0];
    int idx = blockIdx.x * 256 + threadIdx.x;
    if (idx >= NN * 512) return;
    int n = idx >> 9;
    int k = idx & 511;
    if (k < 256) {
        int a = i64 ? (int)atoms[2 * n] : (int)atoms[n];
        A[idx] = type_emb[(long)a * CC + k];
    } else {
        int d = k - 256;
        int g = n / NP;
        float tv = t[g];
        int dd = (d < 128) ? d : d - 128;
        float tf = expf(dd * (-9.210340371976184f / 127.0f));
        float ang = tv * tf;
        A[idx] = (d < 128) ? sinf(ang) : cosf(ang);
    }
}

// ---------------------------------------------------------------------------
// Tiled GEMM: C[M,Nc] = epi(A[M,K] @ W[K,Nc] + bias) (+res). All fp32.
// 64x64 tile, BK=32, 256 threads, 4x4 acc/thread. M%64==0, K%32==0.
// Global loads issue before the barrier -> overlap with previous tile's FMA.
// act: 0 none, 1 relu, 2 silu.
// ---------------------------------------------------------------------------
__global__ __launch_bounds__(256) void gemm_k(
        const float* __restrict__ A, const float* __restrict__ W,
        const float* __restrict__ bias, const float* __restrict__ res,
        float* __restrict__ Cf, int M, int K, int Nc, int act) {
    __shared__ __align__(16) float As[32][64];
    __shared__ __align__(16) float Bs[32][64];
    int tid = threadIdx.x;
    int tx = tid & 15, ty = tid >> 4;
    int m0 = blockIdx.x * 64, n0 = blockIdx.y * 64;
    float acc[4][4] = {{0.f}};
    int am = tid >> 2;           // 0..63
    int ak = (tid & 3) << 3;     // 0,8,16,24
    int bk = tid >> 4;           // 0..15
    int bn = (tid & 15) << 2;    // 0..60

    for (int k0 = 0; k0 < K; k0 += 32) {
        const float* Ap = A + (long)(m0 + am) * K + k0 + ak;
        float4 a1 = *(const float4*)Ap;
        float4 a2 = *(const float4*)(Ap + 4);
        float w1[4], w2[4];
#pragma unroll
        for (int u = 0; u < 4; ++u) {
            int n = n0 + bn + u;
            w1[u] = (n < Nc) ? W[(long)(k0 + bk) * Nc + n] : 0.f;
            w2[u] = (n < Nc) ? W[(long)(k0 + bk + 16) * Nc + n] : 0.f;
        }
        __syncthreads();   // previous tile's readers done (no-op first iter)
        As[ak + 0][am] = a1.x; As[ak + 1][am] = a1.y;
        As[ak + 2][am] = a1.z; As[ak + 3][am] = a1.w;
        As[ak + 4][am] = a2.x; As[ak + 5][am] = a2.y;
        As[ak + 6][am] = a2.z; As[ak + 7][am] = a2.w;
#pragma unroll
        for (int u = 0; u < 4; ++u) {
            Bs[bk][bn + u] = w1[u];
            Bs[bk + 16][bn + u] = w2[u];
        }
        __syncthreads();
#pragma unroll
        for (int k = 0; k < 32; ++k) {
            float4 a = *(const float4*)(&As[k][ty << 2]);
            float4 b = *(const float4*)(&Bs[k][tx << 2]);
            acc[0][0] += a.x * b.x; acc[0][1] += a.x * b.y; acc[0][2] += a.x * b.z; acc[0][3] += a.x * b.w;
            acc[1][0] += a.y * b.x; acc[1][1] += a.y * b.y; acc[1][2] += a.y * b.z; acc[1][3] += a.y * b.w;
            acc[2][0] += a.z * b.x; acc[2][1] += a.z * b.y; acc[2][2] += a.z * b.z; acc[2][3] += a.z * b.w;
            acc[3][0] += a.w * b.x; acc[3][1] += a.w * b.y; acc[3][2] += a.w * b.z; acc[3][3] += a.w * b.w;
        }
    }
#pragma unroll
    for (int i = 0; i < 4; ++i) {
        int m = m0 + (ty << 2) + i;
#pragma unroll
        for (int j = 0; j < 4; ++j) {
            int n = n0 + (tx << 2) + j;
            if (n >= Nc) continue;
            float v = acc[i][j];
            if (bias) v += bias[n];
            if (act == 1) v = fmaxf(v, 0.f);
            else if (act == 2) v = v / (1.f + expf(-v));
            if (res) v += res[(long)m * Nc + n];
            Cf[(long)m * Nc + n] = v;
        }
    }
}

// ---------------------------------------------------------------------------
// Fused GINEConv v2. Block = (graph g, j-quarter jq): 1024 blocks, 128 thr.
// Each thread owns channels c0=tid, c1=tid+128 (weights in registers, 2x FMA
// per LDS broadcast read -> VALU-bound). Edge features for the block's 6 dst
// rows built in LDS once (trig ~8.6K ops/block, negligible; recomputed per
// layer to avoid a 35 MB global buffer). One barrier pair total.
// Semantics == gine_naive (validated R6): z[j] = x[j] + sum_i relu(x[i]+e(i->j)).
// ---------------------------------------------------------------------------
__global__ __launch_bounds__(128) void gine2(
        const float* __restrict__ x, const float* __restrict__ frac,
        const float* __restrict__ lattice, const float* __restrict__ geW,
        const float* __restrict__ geb, float* __restrict__ z, int l) {
    __shared__ __align__(16) float elds[6 * 24 * 60];  // [j_local][i][60]
    __shared__ float fr[72];
    int tid = threadIdx.x;
    int g = blockIdx.x >> 2;
    int jq = blockIdx.x & 3;          // dst rows jq*6 .. jq*6+5
    int c0 = tid, c1 = tid + 128;
    const float* Wg = geW + (long)l * 69 * CC;

    if (tid < 72) fr[tid] = frac[g * 72 + tid];
    __syncthreads();

    // build edge features: fd = (frac[dst j] - frac[src i]) mod 1
    for (int item = tid; item < 6 * 24 * 30; item += 128) {
        int j = item / (24 * 30);
        int rem = item % (24 * 30);
        int i = rem / 30;
        int r = rem % 30;
        int d = r / 10, f = r % 10;
        int jn = jq * 6 + j;
        float fd = fr[jn * 3 + d] - fr[i * 3 + d];
        fd -= floorf(fd);
        float ang = 6.283185307179586f * (float)f * fd;
        elds[(j * 24 + i) * 60 + r] = sinf(ang);
        elds[(j * 24 + i) * 60 + 30 + r] = cosf(ang);
    }

    // per-channel weights -> registers (60 each for 2 channels)
    float4 W0[15], W1[15];
#pragma unroll
    for (int k4 = 0; k4 < 15; ++k4) {
        W0[k4] = make_float4(Wg[(k4 * 4 + 0) * CC + c0], Wg[(k4 * 4 + 1) * CC + c0],
                             Wg[(k4 * 4 + 2) * CC + c0], Wg[(k4 * 4 + 3) * CC + c0]);
        W1[k4] = make_float4(Wg[(k4 * 4 + 0) * CC + c1], Wg[(k4 * 4 + 1) * CC + c1],
                             Wg[(k4 * 4 + 2) * CC + c1], Wg[(k4 * 4 + 3) * CC + c1]);
    }
    float b0 = geb[(long)l * CC + c0];
    float b1 = geb[(long)l * CC + c1];
#pragma unroll
    for (int q = 0; q < 9; ++q) {
        float lv = lattice[(long)g * 9 + q];
        b0 += lv * Wg[(60 + q) * CC + c0];
        b1 += lv * Wg[(60 + q) * CC + c1];
    }
    float xi0[24], xi1[24];
#pragma unroll
    for (int i = 0; i < 24; ++i) {
        xi0[i] = x[(long)(g * NP + i) * CC + c0];
        xi1[i] = x[(long)(g * NP + i) * CC + c1];
    }
    float acc0[6] = {0.f, 0.f, 0.f, 0.f, 0.f, 0.f};
    float acc1[6] = {0.f, 0.f, 0.f, 0.f, 0.f, 0.f};
    __syncthreads();

    for (int j = 0; j < 6; ++j) {
#pragma unroll 2
        for (int i = 0; i < 24; ++i) {
            const float4* e4 = (const float4*)(elds + (j * 24 + i) * 60);
            float v0a = 0.f, v0b = 0.f, v1a = 0.f, v1b = 0.f;
#pragma unroll
            for (int k4 = 0; k4 < 15; k4 += 2) {
                float4 e = e4[k4];
                v0a += e.x * W0[k4].x; v0a += e.y * W0[k4].y;
                v0a += e.z * W0[k4].z; v0a += e.w * W0[k4].w;
                v1a += e.x * W1[k4].x; v1a += e.y * W1[k4].y;
                v1a += e.z * W1[k4].z; v1a += e.w * W1[k4].w;
                if (k4 + 1 < 15) {
                    float4 e2 = e4[k4 + 1];
                    v0b += e2.x * W0[k4 + 1].x; v0b += e2.y * W0[k4 + 1].y;
                    v0b += e2.z * W0[k4 + 1].z; v0b += e2.w * W0[k4 + 1].w;
                    v1b += e2.x * W1[k4 + 1].x; v1b += e2.y * W1[k4 + 1].y;
                    v1b += e2.z * W1[k4 + 1].z; v1b += e2.w * W1[k4 + 1].w;
                }
            }
            float v0 = xi0[i] + b0 + (v0a + v0b);
            float v1 = xi1[i] + b1 + (v1a + v1b);
            acc0[j] += fmaxf(v0, 0.f);
            acc1[j] += fmaxf(v1, 0.f);
        }
    }
#pragma unroll
    for (int j = 0; j < 6; ++j) {
        int node = g * NP + jq * 6 + j;
        z[(long)node * CC + c0] = x[(long)node * CC + c0] + acc0[j];
        z[(long)node * CC + c1] = x[(long)node * CC + c1] + acc1[j];
    }
}

// ---------------------------------------------------------------------------
// BatchNorm, two-stage stats (96 blocks x 64 rows, then combine).
// ---------------------------------------------------------------------------
__global__ void bn_stats1(const float* __restrict__ in, float* __restrict__ part) {
    int c = threadIdx.x, b = blockIdx.x;
    float s = 0.f, q = 0.f;
    for (int r = 0; r < 64; ++r) {
        float v = in[(long)(b * 64 + r) * CC + c];
        s += v; q += v * v;
    }
    part[b * 512 + c] = s;
    part[b * 512 + 256 + c] = q;
}
__global__ void bn_stats2(const float* __restrict__ part, float* __restrict__ stats) {
    int c = threadIdx.x;
    float s = 0.f, q = 0.f;
    for (int b = 0; b < 96; ++b) { s += part[b * 512 + c]; q += part[b * 512 + 256 + c]; }
    float m = s / (float)NN;
    float var = q / (float)NN - m * m;
    stats[c] = m;
    stats[256 + c] = rsqrtf(var + 1e-5f);
}
__global__ void bn_apply(const float* __restrict__ in, const float* __restrict__ stats,
                         const float* __restrict__ gma, const float* __restrict__ bta,
                         const float* __restrict__ add, float* __restrict__ out) {
    long idx = (long)blockIdx.x * 256 + threadIdx.x;
    int c = (int)(idx & 255);
    float v = (in[idx] - stats[c]) * stats[256 + c] * gma[c] + bta[c];
    if (add) v += add[idx];
    out[idx] = v;
}

// ---------------------------------------------------------------------------
// Attention: one thread per (graph, head, query-row)  [validated R6]
// ---------------------------------------------------------------------------
__global__ void attn_naive(const float* __restrict__ qkv, float* __restrict__ o) {
    int idx = blockIdx.x * 256 + threadIdx.x;
    if (idx >= GG * HH * NP) return;
    int g = idx / (HH * NP);
    int rem = idx % (HH * NP);
    int h = rem / NP;
    int row = rem % NP;
    const float* qp = qkv + (long)(g * NP + row) * 768 + h * 64;
    float sc[NP];
    float mx = -1e30f;
    for (int j = 0; j < NP; ++j) {
        const float* kp = qkv + (long)(g * NP + j) * 768 + 256 + h * 64;
        float s = 0.f;
        for (int d = 0; d < 64; ++d) s += qp[d] * kp[d];
        s *= 0.125f;
        sc[j] = s;
        mx = fmaxf(mx, s);
    }
    float sum = 0.f;
    for (int j = 0; j < NP; ++j) { float p = expf(sc[j] - mx); sc[j] = p; sum += p; }
    float inv = 1.f / sum;
    float* op = o + (long)(g * NP + row) * CC + h * 64;
    for (int d = 0; d < 64; ++d) {
        float a = 0.f;
        for (int j = 0; j < NP; ++j)
            a += sc[j] * qkv[(long)(g * NP + j) * 768 + 512 + h * 64 + d];
        op[d] = a * inv;
    }
}

// ---------------------------------------------------------------------------
// LayerNorm, one block (256 threads) per node.
// ---------------------------------------------------------------------------
__global__ __launch_bounds__(256) void ln_kernel(const float* __restrict__ x,
        const float* __restrict__ gma, const float* __restrict__ bta,
        float* __restrict__ out) {
    __shared__ float red[256];
    int n = blockIdx.x, c = threadIdx.x;
    float v = x[(long)n * CC + c];
    red[c] = v;
    __syncthreads();
    for (int s = 128; s > 0; s >>= 1) { if (c < s) red[c] += red[c + s]; __syncthreads(); }
    float m = red[0] * (1.f / 256.f);
    __syncthreads();
    float dv = v - m;
    red[c] = dv * dv;
    __syncthreads();
    for (int s = 128; s > 0; s >>= 1) { if (c < s) red[c] += red[c + s]; __syncthreads(); }
    float var = red[0] * (1.f / 256.f);
    out[(long)n * CC + c] = dv * rsqrtf(var + 1e-5f) * gma[c] + bta[c];
}

__global__ void pool_kernel(const float* __restrict__ hn, float* __restrict__ gf) {
    int g = blockIdx.x, c = threadIdx.x;
    float s = 0.f;
    for (int j = 0; j < NP; ++j) s += hn[(long)(g * NP + j) * CC + c];
    gf[g * CC + c] = s * (1.f / 24.f);
}

// ---------------------------------------------------------------------------
static void gemm(hipStream_t st, const float* A, const float* W, const float* bias,
                 const float* res, float* Cf, int M, int K, int Nc, int act) {
    dim3 grid(M / 64, (Nc + 63) / 64);
    gemm_k<<<grid, 256, 0, st>>>(A, W, bias, res, Cf, M, K, Nc, act);
}

static void run_bn(hipStream_t st, const float* in, float* part, float* stats,
                   const float* g_, const float* b_, const float* add, float* out) {
    bn_stats1<<<96, 256, 0, st>>>(in, part);
    bn_stats2<<<1, 256, 0, st>>>(part, stats);
    bn_apply<<<NN, 256, 0, st>>>(in, stats, g_, b_, add, out);
}

extern "C" void kernel_launch(void* const* d_in, const int* in_sizes, int n_in,
                              void* d_out, int out_size, void* d_ws, size_t ws_size,
                              hipStream_t stream) {
    float* out = (float*)d_out;
    int sigN = out_size < 256 ? out_size : 256;

    static const int EXP_SIZES[46] = {
        256, 18432, 2304, 25600, 131072, 256, 52992, 768, 196608, 768,
        196608, 768, 589824, 2304, 196608, 768, 393216, 1536, 393216, 768,
        768, 768, 768, 768, 768, 768, 256, 256, 32768, 128,
        12800, 100, 32768, 128, 8192, 64, 576, 32768, 128, 8192,
        64, 192, 6144, 6144, 147456, 147456 };
    if (n_in != 46) { signal_k<<<1, 256, 0, stream>>>(out, sigN, 3000.f + 8.f * n_in); return; }
    for (int i = 0; i < 46; ++i)
        if (in_sizes[i] != EXP_SIZES[i]) { signal_k<<<1, 256, 0, stream>>>(out, sigN, 512.f + 8.f * i); return; }
    if (out_size != NN * 100 + GG * 9 + NN * 3) { signal_k<<<1, 256, 0, stream>>>(out, sigN, 7777.f); return; }

    // ---- workspace (layout validated R6/R7) ----
    char* base = (char*)d_ws;
    int* flags = (int*)base;                       // 256 B
    float* f32a = (float*)(base + 256);
    float* x  = f32a;                              // N*256
    float* s1 = x  + (size_t)NN * 256;             // N*256
    float* s2 = s1 + (size_t)NN * 256;             // N*256
    float* big = s2 + (size_t)NN * 256;            // N*768
    float* s3 = big + (size_t)NN * 512;            // alias of big's tail (lifetimes audited)
    float* part = big + (size_t)NN * 768;          // 96*512
    float* stats = part + 96 * 512;                // 512
    float* gf  = stats + 512;                      // G*256
    float* l1b = gf + GG * 256;                    // G*128
    float* l2b = l1b + GG * 128;                   // G*64
    size_t REQ = 256 + ((size_t)NN * 1536 + 96 * 512 + 512 + GG * 448) * 4;
    if (ws_size < REQ) { signal_k<<<1, 256, 0, stream>>>(out, sigN, 9999.f); return; }

    const float* t       = (const float*)d_in[0];
    const float* frac    = (const float*)d_in[1];
    const float* lattice = (const float*)d_in[2];
    const float* type_emb = (const float*)d_in[3];

    detect_int_k<<<1, 256, 0, stream>>>((const unsigned int*)d_in[42], flags);

    // x0 = concat(type_emb[atoms], time_emb) @ naW + nab
    build_A<<<(NN * 512 + 255) / 256, 256, 0, stream>>>(t, type_emb,
        (const unsigned int*)d_in[42], big, flags);
    gemm(stream, big, (const float*)d_in[4], (const float*)d_in[5], nullptr, x, NN, 512, 256, 0);

    for (int l = 0; l < LL; ++l) {
        // GINE: s1 = x + aggr
        gine2<<<GG * 4, 128, 0, stream>>>(x, frac, lattice,
            (const float*)d_in[6], (const float*)d_in[7], s1, l);
        // s2 = silu(s1@gW1+gb1); s3 = s2@gW2+gb2 + x; h1 = BN(s3) -> s2
        gemm(stream, s1, (const float*)d_in[8]  + (long)l * 65536, (const float*)d_in[9]  + l * 256, nullptr, s2, NN, 256, 256, 2);
        gemm(stream, s2, (const float*)d_in[10] + (long)l * 65536, (const float*)d_in[11] + l * 256, x, s3, NN, 256, 256, 0);
        run_bn(stream, s3, part, stats, (const float*)d_in[20] + l * 256, (const float*)d_in[21] + l * 256, nullptr, s2);
        // attention: qkv=big; o=s1; s3 = s1@aoW+aob + x; s1 = h1 + BN(s3)
        gemm(stream, x, (const float*)d_in[12] + (long)l * 196608, (const float*)d_in[13] + l * 768, nullptr, big, NN, 256, 768, 0);
        attn_naive<<<(GG * HH * NP + 255) / 256, 256, 0, stream>>>(big, s1);
        gemm(stream, s1, (const float*)d_in[14] + (long)l * 65536, (const float*)d_in[15] + l * 256, x, s3, NN, 256, 256, 0);
        run_bn(stream, s3, part, stats, (const float*)d_in[22] + l * 256, (const float*)d_in[23] + l * 256, s2, s1);
        // MLP: big = relu(s1@mW1+mb1); s3 = big@mW2+mb2 + s1; x = BN(s3)
        gemm(stream, s1, (const float*)d_in[16] + (long)l * 131072, (const float*)d_in[17] + l * 512, nullptr, big, NN, 256, 512, 1);
        gemm(stream, big, (const float*)d_in[18] + (long)l * 131072, (const float*)d_in[19] + l * 256, s1, s3, NN, 512, 256, 0);
        run_bn(stream, s3, part, stats, (const float*)d_in[24] + l * 256, (const float*)d_in[25] + l * 256, nullptr, x);
    }

    ln_kernel<<<NN, 256, 0, stream>>>(x, (const float*)d_in[26], (const float*)d_in[27], s1);
    pool_kernel<<<GG, 256, 0, stream>>>(s1, gf);

    // types_pred -> out[0 : N*100]
    gemm(stream, s1, (const float*)d_in[28], (const float*)d_in[29], nullptr, s2, NN, 256, 128, 2);
    gemm(stream, s2, (const float*)d_in[30], (const float*)d_in[31], nullptr, out, NN, 128, 100, 0);
    // lattice_pred -> out[N*100 : +G*9]
    gemm(stream, gf,  (const float*)d_in[32], (const float*)d_in[33], nullptr, l1b, GG, 256, 128, 2);
    gemm(stream, l1b, (const float*)d_in[34], (const float*)d_in[35], nullptr, l2b, GG, 128, 64, 2);
    gemm(stream, l2b, (const float*)d_in[36], nullptr, nullptr, out + (size_t)NN * 100, GG, 64, 9, 0);
    // frac_pred -> out[N*100+G*9 : ]
    gemm(stream, s1, (const float*)d_in[37], (const float*)d_in[38], nullptr, s2, NN, 256, 128, 2);
    gemm(stream, s2, (const float*)d_in[39], (const float*)d_in[40], nullptr, s3, NN, 128, 64, 2);
    gemm(stream, s3, (const float*)d_in[41], nullptr, nullptr, out + (size_t)NN * 100 + GG * 9, NN, 64, 3, 0);
}

// Round 9
// 1716.119 us; speedup vs baseline: 6.9402x; 1.0347x over previous
//
#include <hip/hip_runtime.h>
#include <hip/hip_bf16.h>
#include <math.h>

#define GG 256
#define NP 24
#define LL 3
#define CC 256
#define NN (GG*NP)   // 6144 nodes
#define HH 4
#define DH 64

// ---------------------------------------------------------------------------
// Int-width probe (atom_types int32 vs int64), parallel. flags[0]=1 -> int64.
// ---------------------------------------------------------------------------
__global__ void detect_int_k(const unsigned int* __restrict__ at, int* flags) {
    __shared__ int ok;
    if (threadIdx.x == 0) ok = 1;
    __syncthreads();
    if (at[2 * threadIdx.x + 1] != 0u) ok = 0;   // benign race
    __syncthreads();
    if (threadIdx.x == 0) flags[0] = ok;
}

__global__ void signal_k(float* out, int n, float val) {
    int i = blockIdx.x * 256 + threadIdx.x;
    if (i < n) out[i] = val;
}

// ---------------------------------------------------------------------------
// A = [type_emb[atom_types] | time_emb]  (N x 512, fp32)
// ---------------------------------------------------------------------------
__global__ void build_A(const float* __restrict__ t, const float* __restrict__ type_emb,
                        const unsigned int* __restrict__ atoms,
                        float* __restrict__ A, const int* __restrict__ flags) {
    int i64 = flags[0];
    int idx = blockIdx.x * 256 + threadIdx.x;
    if (idx >= NN * 512) return;
    int n = idx >> 9;
    int k = idx & 511;
    if (k < 256) {
        int a = i64 ? (int)atoms[2 * n] : (int)atoms[n];
        A[idx] = type_emb[(long)a * CC + k];
    } else {
        int d = k - 256;
        int g = n / NP;
        float tv = t[g];
        int dd = (d < 128) ? d : d - 128;
        float tf = expf(dd * (-9.210340371976184f / 127.0f));
        float ang = tv * tf;
        A[idx] = (d < 128) ? sinf(ang) : cosf(ang);
    }
}

// ---------------------------------------------------------------------------
// Tiled GEMM: C[M,Nc] = epi(A[M,K] @ W[K,Nc] + bias) (+res). All fp32.
// 64x64 tile, BK=32, 256 threads, 4x4 acc/thread. M%64==0, K%32==0.
// act: 0 none, 1 relu, 2 silu.
// ---------------------------------------------------------------------------
__global__ __launch_bounds__(256) void gemm_k(
        const float* __restrict__ A, const float* __restrict__ W,
        const float* __restrict__ bias, const float* __restrict__ res,
        float* __restrict__ Cf, int M, int K, int Nc, int act) {
    __shared__ __align__(16) float As[32][64];
    __shared__ __align__(16) float Bs[32][64];
    int tid = threadIdx.x;
    int tx = tid & 15, ty = tid >> 4;
    int m0 = blockIdx.x * 64, n0 = blockIdx.y * 64;
    float acc[4][4] = {{0.f}};
    int am = tid >> 2;           // 0..63
    int ak = (tid & 3) << 3;     // 0,8,16,24
    int bk = tid >> 4;           // 0..15
    int bn = (tid & 15) << 2;    // 0..60

    for (int k0 = 0; k0 < K; k0 += 32) {
        const float* Ap = A + (long)(m0 + am) * K + k0 + ak;
        float4 a1 = *(const float4*)Ap;
        float4 a2 = *(const float4*)(Ap + 4);
        float w1[4], w2[4];
#pragma unroll
        for (int u = 0; u < 4; ++u) {
            int n = n0 + bn + u;
            w1[u] = (n < Nc) ? W[(long)(k0 + bk) * Nc + n] : 0.f;
            w2[u] = (n < Nc) ? W[(long)(k0 + bk + 16) * Nc + n] : 0.f;
        }
        __syncthreads();   // previous tile's readers done (no-op first iter)
        As[ak + 0][am] = a1.x; As[ak + 1][am] = a1.y;
        As[ak + 2][am] = a1.z; As[ak + 3][am] = a1.w;
        As[ak + 4][am] = a2.x; As[ak + 5][am] = a2.y;
        As[ak + 6][am] = a2.z; As[ak + 7][am] = a2.w;
#pragma unroll
        for (int u = 0; u < 4; ++u) {
            Bs[bk][bn + u] = w1[u];
            Bs[bk + 16][bn + u] = w2[u];
        }
        __syncthreads();
#pragma unroll
        for (int k = 0; k < 32; ++k) {
            float4 a = *(const float4*)(&As[k][ty << 2]);
            float4 b = *(const float4*)(&Bs[k][tx << 2]);
            acc[0][0] += a.x * b.x; acc[0][1] += a.x * b.y; acc[0][2] += a.x * b.z; acc[0][3] += a.x * b.w;
            acc[1][0] += a.y * b.x; acc[1][1] += a.y * b.y; acc[1][2] += a.y * b.z; acc[1][3] += a.y * b.w;
            acc[2][0] += a.z * b.x; acc[2][1] += a.z * b.y; acc[2][2] += a.z * b.z; acc[2][3] += a.z * b.w;
            acc[3][0] += a.w * b.x; acc[3][1] += a.w * b.y; acc[3][2] += a.w * b.z; acc[3][3] += a.w * b.w;
        }
    }
#pragma unroll
    for (int i = 0; i < 4; ++i) {
        int m = m0 + (ty << 2) + i;
#pragma unroll
        for (int j = 0; j < 4; ++j) {
            int n = n0 + (tx << 2) + j;
            if (n >= Nc) continue;
            float v = acc[i][j];
            if (bias) v += bias[n];
            if (act == 1) v = fmaxf(v, 0.f);
            else if (act == 2) v = v / (1.f + expf(-v));
            if (res) v += res[(long)m * Nc + n];
            Cf[(long)m * Nc + n] = v;
        }
    }
}

// ---------------------------------------------------------------------------
// Fused GINEConv v3. Block = (graph g, j-quarter jq): 1024 blocks, 256 thr,
// ONE channel per thread -> weights need only 60 VGPRs (no spills; R8's
// 2-ch/thread variant needed ~190 regs and spilled at VGPR=104).
// __launch_bounds__(256,4): cap 128 VGPRs, 4 waves/SIMD. LDS 35 KB, 4 blk/CU.
// Semantics == gine_naive (validated R6): z[j] = x[j] + sum_i relu(x[i]+e(i->j)).
// ---------------------------------------------------------------------------
__global__ __launch_bounds__(256, 4) void gine2(
        const float* __restrict__ x, const float* __restrict__ frac,
        const float* __restrict__ lattice, const float* __restrict__ geW,
        const float* __restrict__ geb, float* __restrict__ z, int l) {
    __shared__ __align__(16) float elds[6 * 24 * 60];  // [j_local][i][60]
    __shared__ float fr[72];
    int tid = threadIdx.x;
    int g = blockIdx.x >> 2;
    int jq = blockIdx.x & 3;          // dst rows jq*6 .. jq*6+5
    int c = tid;
    const float* Wg = geW + (long)l * 69 * CC;

    if (tid < 72) fr[tid] = frac[g * 72 + tid];
    __syncthreads();

    // build edge features: fd = (frac[dst j] - frac[src i]) mod 1
    for (int item = tid; item < 6 * 24 * 30; item += 256) {
        int j = item / (24 * 30);
        int rem = item % (24 * 30);
        int i = rem / 30;
        int r = rem % 30;
        int d = r / 10, f = r % 10;
        int jn = jq * 6 + j;
        float fd = fr[jn * 3 + d] - fr[i * 3 + d];
        fd -= floorf(fd);
        float ang = 6.283185307179586f * (float)f * fd;
        elds[(j * 24 + i) * 60 + r] = sinf(ang);
        elds[(j * 24 + i) * 60 + 30 + r] = cosf(ang);
    }

    // this channel's 60 sin/cos weights -> registers
    float4 Wc[15];
#pragma unroll
    for (int k4 = 0; k4 < 15; ++k4)
        Wc[k4] = make_float4(Wg[(k4 * 4 + 0) * CC + c], Wg[(k4 * 4 + 1) * CC + c],
                             Wg[(k4 * 4 + 2) * CC + c], Wg[(k4 * 4 + 3) * CC + c]);
    float base = geb[(long)l * CC + c];
#pragma unroll
    for (int q = 0; q < 9; ++q)
        base += lattice[(long)g * 9 + q] * Wg[(60 + q) * CC + c];

    float xi[24];
#pragma unroll
    for (int i = 0; i < 24; ++i) xi[i] = x[(long)(g * NP + i) * CC + c];
    float acc[6] = {0.f, 0.f, 0.f, 0.f, 0.f, 0.f};
    __syncthreads();

#pragma unroll
    for (int j = 0; j < 6; ++j) {
#pragma unroll 2
        for (int i = 0; i < 24; ++i) {
            const float4* e4 = (const float4*)(elds + (j * 24 + i) * 60);
            float va = 0.f, vb = 0.f, vc2 = 0.f, vd = 0.f;   // 4 chains for ILP
#pragma unroll
            for (int k4 = 0; k4 < 15; k4 += 4) {
                float4 e0 = e4[k4];
                va += e0.x * Wc[k4].x; va += e0.y * Wc[k4].y;
                va += e0.z * Wc[k4].z; va += e0.w * Wc[k4].w;
                if (k4 + 1 < 15) {
                    float4 e1 = e4[k4 + 1];
                    vb += e1.x * Wc[k4 + 1].x; vb += e1.y * Wc[k4 + 1].y;
                    vb += e1.z * Wc[k4 + 1].z; vb += e1.w * Wc[k4 + 1].w;
                }
                if (k4 + 2 < 15) {
                    float4 e2 = e4[k4 + 2];
                    vc2 += e2.x * Wc[k4 + 2].x; vc2 += e2.y * Wc[k4 + 2].y;
                    vc2 += e2.z * Wc[k4 + 2].z; vc2 += e2.w * Wc[k4 + 2].w;
                }
                if (k4 + 3 < 15) {
                    float4 e3 = e4[k4 + 3];
                    vd += e3.x * Wc[k4 + 3].x; vd += e3.y * Wc[k4 + 3].y;
                    vd += e3.z * Wc[k4 + 3].z; vd += e3.w * Wc[k4 + 3].w;
                }
            }
            float v = xi[i] + base + ((va + vb) + (vc2 + vd));
            acc[j] += fmaxf(v, 0.f);
        }
    }
#pragma unroll
    for (int j = 0; j < 6; ++j) {
        int node = g * NP + jq * 6 + j;
        z[(long)node * CC + c] = x[(long)node * CC + c] + acc[j];
    }
}

// ---------------------------------------------------------------------------
// BatchNorm, two-stage stats (96 blocks x 64 rows, then combine).
// ---------------------------------------------------------------------------
__global__ void bn_stats1(const float* __restrict__ in, float* __restrict__ part) {
    int c = threadIdx.x, b = blockIdx.x;
    float s = 0.f, q = 0.f;
    for (int r = 0; r < 64; ++r) {
        float v = in[(long)(b * 64 + r) * CC + c];
        s += v; q += v * v;
    }
    part[b * 512 + c] = s;
    part[b * 512 + 256 + c] = q;
}
__global__ void bn_stats2(const float* __restrict__ part, float* __restrict__ stats) {
    int c = threadIdx.x;
    float s = 0.f, q = 0.f;
    for (int b = 0; b < 96; ++b) { s += part[b * 512 + c]; q += part[b * 512 + 256 + c]; }
    float m = s / (float)NN;
    float var = q / (float)NN - m * m;
    stats[c] = m;
    stats[256 + c] = rsqrtf(var + 1e-5f);
}
__global__ void bn_apply(const float* __restrict__ in, const float* __restrict__ stats,
                         const float* __restrict__ gma, const float* __restrict__ bta,
                         const float* __restrict__ add, float* __restrict__ out) {
    long idx = (long)blockIdx.x * 256 + threadIdx.x;
    int c = (int)(idx & 255);
    float v = (in[idx] - stats[c]) * stats[256 + c] * gma[c] + bta[c];
    if (add) v += add[idx];
    out[idx] = v;
}

// ---------------------------------------------------------------------------
// Attention: one thread per (graph, head, query-row)  [validated R6]
// ---------------------------------------------------------------------------
__global__ void attn_naive(const float* __restrict__ qkv, float* __restrict__ o) {
    int idx = blockIdx.x * 256 + threadIdx.x;
    if (idx >= GG * HH * NP) return;
    int g = idx / (HH * NP);
    int rem = idx % (HH * NP);
    int h = rem / NP;
    int row = rem % NP;
    const float* qp = qkv + (long)(g * NP + row) * 768 + h * 64;
    float sc[NP];
    float mx = -1e30f;
    for (int j = 0; j < NP; ++j) {
        const float* kp = qkv + (long)(g * NP + j) * 768 + 256 + h * 64;
        float s = 0.f;
        for (int d = 0; d < 64; ++d) s += qp[d] * kp[d];
        s *= 0.125f;
        sc[j] = s;
        mx = fmaxf(mx, s);
    }
    float sum = 0.f;
    for (int j = 0; j < NP; ++j) { float p = expf(sc[j] - mx); sc[j] = p; sum += p; }
    float inv = 1.f / sum;
    float* op = o + (long)(g * NP + row) * CC + h * 64;
    for (int d = 0; d < 64; ++d) {
        float a = 0.f;
        for (int j = 0; j < NP; ++j)
            a += sc[j] * qkv[(long)(g * NP + j) * 768 + 512 + h * 64 + d];
        op[d] = a * inv;
    }
}

// ---------------------------------------------------------------------------
// LayerNorm, one block (256 threads) per node.
// ---------------------------------------------------------------------------
__global__ __launch_bounds__(256) void ln_kernel(const float* __restrict__ x,
        const float* __restrict__ gma, const float* __restrict__ bta,
        float* __restrict__ out) {
    __shared__ float red[256];
    int n = blockIdx.x, c = threadIdx.x;
    float v = x[(long)n * CC + c];
    red[c] = v;
    __syncthreads();
    for (int s = 128; s > 0; s >>= 1) { if (c < s) red[c] += red[c + s]; __syncthreads(); }
    float m = red[0] * (1.f / 256.f);
    __syncthreads();
    float dv = v - m;
    red[c] = dv * dv;
    __syncthreads();
    for (int s = 128; s > 0; s >>= 1) { if (c < s) red[c] += red[c + s]; __syncthreads(); }
    float var = red[0] * (1.f / 256.f);
    out[(long)n * CC + c] = dv * rsqrtf(var + 1e-5f) * gma[c] + bta[c];
}

__global__ void pool_kernel(const float* __restrict__ hn, float* __restrict__ gf) {
    int g = blockIdx.x, c = threadIdx.x;
    float s = 0.f;
    for (int j = 0; j < NP; ++j) s += hn[(long)(g * NP + j) * CC + c];
    gf[g * CC + c] = s * (1.f / 24.f);
}

// ---------------------------------------------------------------------------
static void gemm(hipStream_t st, const float* A, const float* W, const float* bias,
                 const float* res, float* Cf, int M, int K, int Nc, int act) {
    dim3 grid(M / 64, (Nc + 63) / 64);
    gemm_k<<<grid, 256, 0, st>>>(A, W, bias, res, Cf, M, K, Nc, act);
}

static void run_bn(hipStream_t st, const float* in, float* part, float* stats,
                   const float* g_, const float* b_, const float* add, float* out) {
    bn_stats1<<<96, 256, 0, st>>>(in, part);
    bn_stats2<<<1, 256, 0, st>>>(part, stats);
    bn_apply<<<NN, 256, 0, st>>>(in, stats, g_, b_, add, out);
}

extern "C" void kernel_launch(void* const* d_in, const int* in_sizes, int n_in,
                              void* d_out, int out_size, void* d_ws, size_t ws_size,
                              hipStream_t stream) {
    float* out = (float*)d_out;
    int sigN = out_size < 256 ? out_size : 256;

    static const int EXP_SIZES[46] = {
        256, 18432, 2304, 25600, 131072, 256, 52992, 768, 196608, 768,
        196608, 768, 589824, 2304, 196608, 768, 393216, 1536, 393216, 768,
        768, 768, 768, 768, 768, 768, 256, 256, 32768, 128,
        12800, 100, 32768, 128, 8192, 64, 576, 32768, 128, 8192,
        64, 192, 6144, 6144, 147456, 147456 };
    if (n_in != 46) { signal_k<<<1, 256, 0, stream>>>(out, sigN, 3000.f + 8.f * n_in); return; }
    for (int i = 0; i < 46; ++i)
        if (in_sizes[i] != EXP_SIZES[i]) { signal_k<<<1, 256, 0, stream>>>(out, sigN, 512.f + 8.f * i); return; }
    if (out_size != NN * 100 + GG * 9 + NN * 3) { signal_k<<<1, 256, 0, stream>>>(out, sigN, 7777.f); return; }

    // ---- workspace (layout validated R6/R7) ----
    char* base = (char*)d_ws;
    int* flags = (int*)base;                       // 256 B
    float* f32a = (float*)(base + 256);
    float* x  = f32a;                              // N*256
    float* s1 = x  + (size_t)NN * 256;             // N*256
    float* s2 = s1 + (size_t)NN * 256;             // N*256
    float* big = s2 + (size_t)NN * 256;            // N*768
    float* s3 = big + (size_t)NN * 512;            // alias of big's tail (lifetimes audited)
    float* part = big + (size_t)NN * 768;          // 96*512
    float* stats = part + 96 * 512;                // 512
    float* gf  = stats + 512;                      // G*256
    float* l1b = gf + GG * 256;                    // G*128
    float* l2b = l1b + GG * 128;                   // G*64
    size_t REQ = 256 + ((size_t)NN * 1536 + 96 * 512 + 512 + GG * 448) * 4;
    if (ws_size < REQ) { signal_k<<<1, 256, 0, stream>>>(out, sigN, 9999.f); return; }

    const float* t       = (const float*)d_in[0];
    const float* frac    = (const float*)d_in[1];
    const float* lattice = (const float*)d_in[2];
    const float* type_emb = (const float*)d_in[3];

    detect_int_k<<<1, 256, 0, stream>>>((const unsigned int*)d_in[42], flags);

    // x0 = concat(type_emb[atoms], time_emb) @ naW + nab
    build_A<<<(NN * 512 + 255) / 256, 256, 0, stream>>>(t, type_emb,
        (const unsigned int*)d_in[42], big, flags);
    gemm(stream, big, (const float*)d_in[4], (const float*)d_in[5], nullptr, x, NN, 512, 256, 0);

    for (int l = 0; l < LL; ++l) {
        // GINE: s1 = x + aggr
        gine2<<<GG * 4, 256, 0, stream>>>(x, frac, lattice,
            (const float*)d_in[6], (const float*)d_in[7], s1, l);
        // s2 = silu(s1@gW1+gb1); s3 = s2@gW2+gb2 + x; h1 = BN(s3) -> s2
        gemm(stream, s1, (const float*)d_in[8]  + (long)l * 65536, (const float*)d_in[9]  + l * 256, nullptr, s2, NN, 256, 256, 2);
        gemm(stream, s2, (const float*)d_in[10] + (long)l * 65536, (const float*)d_in[11] + l * 256, x, s3, NN, 256, 256, 0);
        run_bn(stream, s3, part, stats, (const float*)d_in[20] + l * 256, (const float*)d_in[21] + l * 256, nullptr, s2);
        // attention: qkv=big; o=s1; s3 = s1@aoW+aob + x; s1 = h1 + BN(s3)
        gemm(stream, x, (const float*)d_in[12] + (long)l * 196608, (const float*)d_in[13] + l * 768, nullptr, big, NN, 256, 768, 0);
        attn_naive<<<(GG * HH * NP + 255) / 256, 256, 0, stream>>>(big, s1);
        gemm(stream, s1, (const float*)d_in[14] + (long)l * 65536, (const float*)d_in[15] + l * 256, x, s3, NN, 256, 256, 0);
        run_bn(stream, s3, part, stats, (const float*)d_in[22] + l * 256, (const float*)d_in[23] + l * 256, s2, s1);
        // MLP: big = relu(s1@mW1+mb1); s3 = big@mW2+mb2 + s1; x = BN(s3)
        gemm(stream, s1, (const float*)d_in[16] + (long)l * 131072, (const float*)d_in[17] + l * 512, nullptr, big, NN, 256, 512, 1);
        gemm(stream, big, (const float*)d_in[18] + (long)l * 131072, (const float*)d_in[19] + l * 256, s1, s3, NN, 512, 256, 0);
        run_bn(stream, s3, part, stats, (const float*)d_in[24] + l * 256, (const float*)d_in[25] + l * 256, nullptr, x);
    }

    ln_kernel<<<NN, 256, 0, stream>>>(x, (const float*)d_in[26], (const float*)d_in[27], s1);
    pool_kernel<<<GG, 256, 0, stream>>>(s1, gf);

    // types_pred -> out[0 : N*100]
    gemm(stream, s1, (const float*)d_in[28], (const float*)d_in[29], nullptr, s2, NN, 256, 128, 2);
    gemm(stream, s2, (const float*)d_in[30], (const float*)d_in[31], nullptr, out, NN, 128, 100, 0);
    // lattice_pred -> out[N*100 : +G*9]
    gemm(stream, gf,  (const float*)d_in[32], (const float*)d_in[33], nullptr, l1b, GG, 256, 128, 2);
    gemm(stream, l1b, (const float*)d_in[34], (const float*)d_in[35], nullptr, l2b, GG, 128, 64, 2);
    gemm(stream, l2b, (const float*)d_in[36], nullptr, nullptr, out + (size_t)NN * 100, GG, 64, 9, 0);
    // frac_pred -> out[N*100+G*9 : ]
    gemm(stream, s1, (const float*)d_in[37], (const float*)d_in[38], nullptr, s2, NN, 256, 128, 2);
    gemm(stream, s2, (const float*)d_in[39], (const float*)d_in[40], nullptr, s3, NN, 128, 64, 2);
    gemm(stream, s3, (const float*)d_in[41], nullptr, nullptr, out + (size_t)NN * 100 + GG * 9, NN, 64, 3, 0);
}

// Round 10
// 1455.118 us; speedup vs baseline: 8.1850x; 1.1794x over previous
//
#include <hip/hip_runtime.h>
#include <hip/hip_bf16.h>
#include <math.h>

#define GG 256
#define NP 24
#define LL 3
#define CC 256
#define NN (GG*NP)   // 6144 nodes
#define HH 4
#define DH 64

// ---------------------------------------------------------------------------
// Int-width probe (atom_types int32 vs int64), parallel. flags[0]=1 -> int64.
// ---------------------------------------------------------------------------
__global__ void detect_int_k(const unsigned int* __restrict__ at, int* flags) {
    __shared__ int ok;
    if (threadIdx.x == 0) ok = 1;
    __syncthreads();
    if (at[2 * threadIdx.x + 1] != 0u) ok = 0;   // benign race
    __syncthreads();
    if (threadIdx.x == 0) flags[0] = ok;
}

__global__ void signal_k(float* out, int n, float val) {
    int i = blockIdx.x * 256 + threadIdx.x;
    if (i < n) out[i] = val;
}

// ---------------------------------------------------------------------------
// A = [type_emb[atom_types] | time_emb]  (N x 512, fp32)
// ---------------------------------------------------------------------------
__global__ void build_A(const float* __restrict__ t, const float* __restrict__ type_emb,
                        const unsigned int* __restrict__ atoms,
                        float* __restrict__ A, const int* __restrict__ flags) {
    int i64 = flags[0];
    int idx = blockIdx.x * 256 + threadIdx.x;
    if (idx >= NN * 512) return;
    int n = idx >> 9;
    int k = idx & 511;
    if (k < 256) {
        int a = i64 ? (int)atoms[2 * n] : (int)atoms[n];
        A[idx] = type_emb[(long)a * CC + k];
    } else {
        int d = k - 256;
        int g = n / NP;
        float tv = t[g];
        int dd = (d < 128) ? d : d - 128;
        float tf = expf(dd * (-9.210340371976184f / 127.0f));
        float ang = tv * tf;
        A[idx] = (d < 128) ? sinf(ang) : cosf(ang);
    }
}

// ---------------------------------------------------------------------------
// Tiled GEMM: C[M,Nc] = epi(A[M,K] @ W[K,Nc] + bias) (+res). All fp32.
// 64x64 tile, BK=32, 256 threads, 4x4 acc/thread. (unchanged from R9)
// ---------------------------------------------------------------------------
__global__ __launch_bounds__(256) void gemm_k(
        const float* __restrict__ A, const float* __restrict__ W,
        const float* __restrict__ bias, const float* __restrict__ res,
        float* __restrict__ Cf, int M, int K, int Nc, int act) {
    __shared__ __align__(16) float As[32][64];
    __shared__ __align__(16) float Bs[32][64];
    int tid = threadIdx.x;
    int tx = tid & 15, ty = tid >> 4;
    int m0 = blockIdx.x * 64, n0 = blockIdx.y * 64;
    float acc[4][4] = {{0.f}};
    int am = tid >> 2;
    int ak = (tid & 3) << 3;
    int bk = tid >> 4;
    int bn = (tid & 15) << 2;

    for (int k0 = 0; k0 < K; k0 += 32) {
        const float* Ap = A + (long)(m0 + am) * K + k0 + ak;
        float4 a1 = *(const float4*)Ap;
        float4 a2 = *(const float4*)(Ap + 4);
        float w1[4], w2[4];
#pragma unroll
        for (int u = 0; u < 4; ++u) {
            int n = n0 + bn + u;
            w1[u] = (n < Nc) ? W[(long)(k0 + bk) * Nc + n] : 0.f;
            w2[u] = (n < Nc) ? W[(long)(k0 + bk + 16) * Nc + n] : 0.f;
        }
        __syncthreads();
        As[ak + 0][am] = a1.x; As[ak + 1][am] = a1.y;
        As[ak + 2][am] = a1.z; As[ak + 3][am] = a1.w;
        As[ak + 4][am] = a2.x; As[ak + 5][am] = a2.y;
        As[ak + 6][am] = a2.z; As[ak + 7][am] = a2.w;
#pragma unroll
        for (int u = 0; u < 4; ++u) {
            Bs[bk][bn + u] = w1[u];
            Bs[bk + 16][bn + u] = w2[u];
        }
        __syncthreads();
#pragma unroll
        for (int k = 0; k < 32; ++k) {
            float4 a = *(const float4*)(&As[k][ty << 2]);
            float4 b = *(const float4*)(&Bs[k][tx << 2]);
            acc[0][0] += a.x * b.x; acc[0][1] += a.x * b.y; acc[0][2] += a.x * b.z; acc[0][3] += a.x * b.w;
            acc[1][0] += a.y * b.x; acc[1][1] += a.y * b.y; acc[1][2] += a.y * b.z; acc[1][3] += a.y * b.w;
            acc[2][0] += a.z * b.x; acc[2][1] += a.z * b.y; acc[2][2] += a.z * b.z; acc[2][3] += a.z * b.w;
            acc[3][0] += a.w * b.x; acc[3][1] += a.w * b.y; acc[3][2] += a.w * b.z; acc[3][3] += a.w * b.w;
        }
    }
#pragma unroll
    for (int i = 0; i < 4; ++i) {
        int m = m0 + (ty << 2) + i;
#pragma unroll
        for (int j = 0; j < 4; ++j) {
            int n = n0 + (tx << 2) + j;
            if (n >= Nc) continue;
            float v = acc[i][j];
            if (bias) v += bias[n];
            if (act == 1) v = fmaxf(v, 0.f);
            else if (act == 2) v = v / (1.f + expf(-v));
            if (res) v += res[(long)m * Nc + n];
            Cf[(long)m * Nc + n] = v;
        }
    }
}

// ---------------------------------------------------------------------------
// Fused GINEConv v4: 2 channels/thread to double FMA per LDS broadcast read
// (R9's 1ch/thread was LDS-issue-bound at 4 FMA/b128). __launch_bounds__(128,2)
// -> 256-VGPR budget so the ~150-reg set (W0+W1=120) does NOT spill (R8's
// failure mode). Block = (graph, j-quarter), 1024 blocks, 128 threads.
// i-outer loop: x row load hoisted, no xi[] array.
// ---------------------------------------------------------------------------
__global__ __launch_bounds__(128, 2) void gine3(
        const float* __restrict__ x, const float* __restrict__ frac,
        const float* __restrict__ lattice, const float* __restrict__ geW,
        const float* __restrict__ geb, float* __restrict__ z, int l) {
    __shared__ __align__(16) float elds[6 * 24 * 60];  // [j_local][i][60], 34.6 KB
    __shared__ float fr[72];
    int tid = threadIdx.x;
    int g = blockIdx.x >> 2;
    int jq = blockIdx.x & 3;          // dst rows jq*6 .. jq*6+5
    int c0 = tid, c1 = tid + 128;
    const float* Wg = geW + (long)l * 69 * CC;

    if (tid < 72) fr[tid] = frac[g * 72 + tid];
    __syncthreads();

    // build edge features: fd = (frac[dst j] - frac[src i]) mod 1
    for (int item = tid; item < 6 * 24 * 30; item += 128) {
        int j = item / (24 * 30);
        int rem = item % (24 * 30);
        int i = rem / 30;
        int r = rem % 30;
        int d = r / 10, f = r % 10;
        int jn = jq * 6 + j;
        float fd = fr[jn * 3 + d] - fr[i * 3 + d];
        fd -= floorf(fd);
        float ang = 6.283185307179586f * (float)f * fd;
        elds[(j * 24 + i) * 60 + r] = sinf(ang);
        elds[(j * 24 + i) * 60 + 30 + r] = cosf(ang);
    }

    // both channels' 60 sin/cos weights -> registers (120 VGPRs)
    float4 W0[15], W1[15];
#pragma unroll
    for (int k4 = 0; k4 < 15; ++k4) {
        W0[k4] = make_float4(Wg[(k4 * 4 + 0) * CC + c0], Wg[(k4 * 4 + 1) * CC + c0],
                             Wg[(k4 * 4 + 2) * CC + c0], Wg[(k4 * 4 + 3) * CC + c0]);
        W1[k4] = make_float4(Wg[(k4 * 4 + 0) * CC + c1], Wg[(k4 * 4 + 1) * CC + c1],
                             Wg[(k4 * 4 + 2) * CC + c1], Wg[(k4 * 4 + 3) * CC + c1]);
    }
    float base0 = geb[(long)l * CC + c0];
    float base1 = geb[(long)l * CC + c1];
#pragma unroll
    for (int q = 0; q < 9; ++q) {
        float lv = lattice[(long)g * 9 + q];
        base0 += lv * Wg[(60 + q) * CC + c0];
        base1 += lv * Wg[(60 + q) * CC + c1];
    }
    float acc0[6] = {0.f, 0.f, 0.f, 0.f, 0.f, 0.f};
    float acc1[6] = {0.f, 0.f, 0.f, 0.f, 0.f, 0.f};
    __syncthreads();

    for (int i = 0; i < 24; ++i) {
        float t0 = x[(long)(g * NP + i) * CC + c0] + base0;
        float t1 = x[(long)(g * NP + i) * CC + c1] + base1;
#pragma unroll
        for (int j = 0; j < 6; ++j) {
            const float4* e4 = (const float4*)(elds + (j * 24 + i) * 60);
            float v0a = 0.f, v0b = 0.f, v1a = 0.f, v1b = 0.f;
#pragma unroll
            for (int k4 = 0; k4 < 15; k4 += 2) {
                float4 ea = e4[k4];
                v0a += ea.x * W0[k4].x; v0a += ea.y * W0[k4].y;
                v0a += ea.z * W0[k4].z; v0a += ea.w * W0[k4].w;
                v1a += ea.x * W1[k4].x; v1a += ea.y * W1[k4].y;
                v1a += ea.z * W1[k4].z; v1a += ea.w * W1[k4].w;
                if (k4 + 1 < 15) {
                    float4 eb = e4[k4 + 1];
                    v0b += eb.x * W0[k4 + 1].x; v0b += eb.y * W0[k4 + 1].y;
                    v0b += eb.z * W0[k4 + 1].z; v0b += eb.w * W0[k4 + 1].w;
                    v1b += eb.x * W1[k4 + 1].x; v1b += eb.y * W1[k4 + 1].y;
                    v1b += eb.z * W1[k4 + 1].z; v1b += eb.w * W1[k4 + 1].w;
                }
            }
            acc0[j] += fmaxf(t0 + (v0a + v0b), 0.f);
            acc1[j] += fmaxf(t1 + (v1a + v1b), 0.f);
        }
    }
#pragma unroll
    for (int j = 0; j < 6; ++j) {
        int node = g * NP + jq * 6 + j;
        z[(long)node * CC + c0] = x[(long)node * CC + c0] + acc0[j];
        z[(long)node * CC + c1] = x[(long)node * CC + c1] + acc1[j];
    }
}

// ---------------------------------------------------------------------------
// BatchNorm, two-stage stats (96 blocks x 64 rows, then combine).
// ---------------------------------------------------------------------------
__global__ void bn_stats1(const float* __restrict__ in, float* __restrict__ part) {
    int c = threadIdx.x, b = blockIdx.x;
    float s = 0.f, q = 0.f;
    for (int r = 0; r < 64; ++r) {
        float v = in[(long)(b * 64 + r) * CC + c];
        s += v; q += v * v;
    }
    part[b * 512 + c] = s;
    part[b * 512 + 256 + c] = q;
}
__global__ void bn_stats2(const float* __restrict__ part, float* __restrict__ stats) {
    int c = threadIdx.x;
    float s = 0.f, q = 0.f;
    for (int b = 0; b < 96; ++b) { s += part[b * 512 + c]; q += part[b * 512 + 256 + c]; }
    float m = s / (float)NN;
    float var = q / (float)NN - m * m;
    stats[c] = m;
    stats[256 + c] = rsqrtf(var + 1e-5f);
}
__global__ void bn_apply(const float* __restrict__ in, const float* __restrict__ stats,
                         const float* __restrict__ gma, const float* __restrict__ bta,
                         const float* __restrict__ add, float* __restrict__ out) {
    long idx = (long)blockIdx.x * 256 + threadIdx.x;
    int c = (int)(idx & 255);
    float v = (in[idx] - stats[c]) * stats[256 + c] * gma[c] + bta[c];
    if (add) v += add[idx];
    out[idx] = v;
}

// ---------------------------------------------------------------------------
// Attention v2: one block per graph (256 blocks, 256 threads). K/V in LDS
// (padded layout (row*4+h)*68+d: h-offset = 4 banks -> conflict-free), q and
// scores in registers (96 active threads, ~100 VGPR, NO scratch - R9's
// attn_naive spilled everything at VGPR=36, 39 MB scratch writes).
// ---------------------------------------------------------------------------
__global__ __launch_bounds__(256, 2) void attn2(const float* __restrict__ qkv,
                                                float* __restrict__ o) {
    __shared__ __align__(16) float Kl[24 * 4 * 68];   // 6528 floats, 25.5 KB
    __shared__ __align__(16) float Vl[24 * 4 * 68];
    __shared__ float S[4 * 24 * 25];                  // normalized P, padded
    int tid = threadIdx.x, g = blockIdx.x;

    // stage K and V: row = node-in-graph, per-head-padded layout
    const float4* qkv4 = (const float4*)(qkv + (long)g * NP * 768);
    for (int idx = tid; idx < 24 * 128; idx += 256) {
        int row = idx >> 7;            // 0..23
        int c4 = idx & 127;            // 0..63 = K, 64..127 = V
        int isV = c4 >> 6;
        int cc = c4 & 63;              // float4 index within 256 channels
        int h = cc >> 4, d4 = cc & 15;
        float4 val = qkv4[row * 192 + 64 + c4];
        float* dst = (isV ? Vl : Kl) + (row * 4 + h) * 68 + d4 * 4;
        *(float4*)dst = val;
    }
    __syncthreads();

    // phase 1: scores + softmax. thread (h = tid&3, i = tid>>2), 96 active.
    if (tid < 96) {
        int h = tid & 3, i = tid >> 2;
        const float4* qp = (const float4*)(qkv + ((long)(g * NP + i)) * 768 + h * 64);
        float4 q[16];
#pragma unroll
        for (int k = 0; k < 16; ++k) q[k] = qp[k];
        float sc[24];
        float mx = -1e30f;
        for (int j = 0; j < 24; ++j) {
            const float4* kp = (const float4*)(Kl + (j * 4 + h) * 68);
            float da = 0.f, db = 0.f;
#pragma unroll
            for (int k = 0; k < 16; k += 2) {
                float4 kv = kp[k];
                da += q[k].x * kv.x; da += q[k].y * kv.y;
                da += q[k].z * kv.z; da += q[k].w * kv.w;
                float4 kv2 = kp[k + 1];
                db += q[k + 1].x * kv2.x; db += q[k + 1].y * kv2.y;
                db += q[k + 1].z * kv2.z; db += q[k + 1].w * kv2.w;
            }
            float s = (da + db) * 0.125f;
            sc[j] = s;
            mx = fmaxf(mx, s);
        }
        float sum = 0.f;
#pragma unroll
        for (int j = 0; j < 24; ++j) { float p = expf(sc[j] - mx); sc[j] = p; sum += p; }
        float inv = 1.f / sum;
#pragma unroll
        for (int j = 0; j < 24; ++j) S[(h * 24 + i) * 25 + j] = sc[j] * inv;
    }
    __syncthreads();

    // phase 3: thread (h = tid>>6, d = tid&63) computes o[:, h*64+d].
    int h = tid >> 6, d = tid & 63;
    for (int i = 0; i < 24; ++i) {
        const float* Sp = S + (h * 24 + i) * 25;
        float a0 = 0.f, a1 = 0.f;
#pragma unroll
        for (int j = 0; j < 24; j += 2) {
            a0 += Sp[j] * Vl[(j * 4 + h) * 68 + d];
            a1 += Sp[j + 1] * Vl[((j + 1) * 4 + h) * 68 + d];
        }
        o[(long)(g * NP + i) * CC + h * 64 + d] = a0 + a1;
    }
}

// ---------------------------------------------------------------------------
// LayerNorm, one block (256 threads) per node.
// ---------------------------------------------------------------------------
__global__ __launch_bounds__(256) void ln_kernel(const float* __restrict__ x,
        const float* __restrict__ gma, const float* __restrict__ bta,
        float* __restrict__ out) {
    __shared__ float red[256];
    int n = blockIdx.x, c = threadIdx.x;
    float v = x[(long)n * CC + c];
    red[c] = v;
    __syncthreads();
    for (int s = 128; s > 0; s >>= 1) { if (c < s) red[c] += red[c + s]; __syncthreads(); }
    float m = red[0] * (1.f / 256.f);
    __syncthreads();
    float dv = v - m;
    red[c] = dv * dv;
    __syncthreads();
    for (int s = 128; s > 0; s >>= 1) { if (c < s) red[c] += red[c + s]; __syncthreads(); }
    float var = red[0] * (1.f / 256.f);
    out[(long)n * CC + c] = dv * rsqrtf(var + 1e-5f) * gma[c] + bta[c];
}

__global__ void pool_kernel(const float* __restrict__ hn, float* __restrict__ gf) {
    int g = blockIdx.x, c = threadIdx.x;
    float s = 0.f;
    for (int j = 0; j < NP; ++j) s += hn[(long)(g * NP + j) * CC + c];
    gf[g * CC + c] = s * (1.f / 24.f);
}

// ---------------------------------------------------------------------------
static void gemm(hipStream_t st, const float* A, const float* W, const float* bias,
                 const float* res, float* Cf, int M, int K, int Nc, int act) {
    dim3 grid(M / 64, (Nc + 63) / 64);
    gemm_k<<<grid, 256, 0, st>>>(A, W, bias, res, Cf, M, K, Nc, act);
}

static void run_bn(hipStream_t st, const float* in, float* part, float* stats,
                   const float* g_, const float* b_, const float* add, float* out) {
    bn_stats1<<<96, 256, 0, st>>>(in, part);
    bn_stats2<<<1, 256, 0, st>>>(part, stats);
    bn_apply<<<NN, 256, 0, st>>>(in, stats, g_, b_, add, out);
}

extern "C" void kernel_launch(void* const* d_in, const int* in_sizes, int n_in,
                              void* d_out, int out_size, void* d_ws, size_t ws_size,
                              hipStream_t stream) {
    float* out = (float*)d_out;
    int sigN = out_size < 256 ? out_size : 256;

    static const int EXP_SIZES[46] = {
        256, 18432, 2304, 25600, 131072, 256, 52992, 768, 196608, 768,
        196608, 768, 589824, 2304, 196608, 768, 393216, 1536, 393216, 768,
        768, 768, 768, 768, 768, 768, 256, 256, 32768, 128,
        12800, 100, 32768, 128, 8192, 64, 576, 32768, 128, 8192,
        64, 192, 6144, 6144, 147456, 147456 };
    if (n_in != 46) { signal_k<<<1, 256, 0, stream>>>(out, sigN, 3000.f + 8.f * n_in); return; }
    for (int i = 0; i < 46; ++i)
        if (in_sizes[i] != EXP_SIZES[i]) { signal_k<<<1, 256, 0, stream>>>(out, sigN, 512.f + 8.f * i); return; }
    if (out_size != NN * 100 + GG * 9 + NN * 3) { signal_k<<<1, 256, 0, stream>>>(out, sigN, 7777.f); return; }

    // ---- workspace (layout validated R6-R9) ----
    char* base = (char*)d_ws;
    int* flags = (int*)base;                       // 256 B
    float* f32a = (float*)(base + 256);
    float* x  = f32a;                              // N*256
    float* s1 = x  + (size_t)NN * 256;             // N*256
    float* s2 = s1 + (size_t)NN * 256;             // N*256
    float* big = s2 + (size_t)NN * 256;            // N*768
    float* s3 = big + (size_t)NN * 512;            // alias of big's tail (lifetimes audited)
    float* part = big + (size_t)NN * 768;          // 96*512
    float* stats = part + 96 * 512;                // 512
    float* gf  = stats + 512;                      // G*256
    float* l1b = gf + GG * 256;                    // G*128
    float* l2b = l1b + GG * 128;                   // G*64
    size_t REQ = 256 + ((size_t)NN * 1536 + 96 * 512 + 512 + GG * 448) * 4;
    if (ws_size < REQ) { signal_k<<<1, 256, 0, stream>>>(out, sigN, 9999.f); return; }

    const float* t       = (const float*)d_in[0];
    const float* frac    = (const float*)d_in[1];
    const float* lattice = (const float*)d_in[2];
    const float* type_emb = (const float*)d_in[3];

    detect_int_k<<<1, 256, 0, stream>>>((const unsigned int*)d_in[42], flags);

    // x0 = concat(type_emb[atoms], time_emb) @ naW + nab
    build_A<<<(NN * 512 + 255) / 256, 256, 0, stream>>>(t, type_emb,
        (const unsigned int*)d_in[42], big, flags);
    gemm(stream, big, (const float*)d_in[4], (const float*)d_in[5], nullptr, x, NN, 512, 256, 0);

    for (int l = 0; l < LL; ++l) {
        // GINE: s1 = x + aggr
        gine3<<<GG * 4, 128, 0, stream>>>(x, frac, lattice,
            (const float*)d_in[6], (const float*)d_in[7], s1, l);
        // s2 = silu(s1@gW1+gb1); s3 = s2@gW2+gb2 + x; h1 = BN(s3) -> s2
        gemm(stream, s1, (const float*)d_in[8]  + (long)l * 65536, (const float*)d_in[9]  + l * 256, nullptr, s2, NN, 256, 256, 2);
        gemm(stream, s2, (const float*)d_in[10] + (long)l * 65536, (const float*)d_in[11] + l * 256, x, s3, NN, 256, 256, 0);
        run_bn(stream, s3, part, stats, (const float*)d_in[20] + l * 256, (const float*)d_in[21] + l * 256, nullptr, s2);
        // attention: qkv=big; o=s1; s3 = s1@aoW+aob + x; s1 = h1 + BN(s3)
        gemm(stream, x, (const float*)d_in[12] + (long)l * 196608, (const float*)d_in[13] + l * 768, nullptr, big, NN, 256, 768, 0);
        attn2<<<GG, 256, 0, stream>>>(big, s1);
        gemm(stream, s1, (const float*)d_in[14] + (long)l * 65536, (const float*)d_in[15] + l * 256, x, s3, NN, 256, 256, 0);
        run_bn(stream, s3, part, stats, (const float*)d_in[22] + l * 256, (const float*)d_in[23] + l * 256, s2, s1);
        // MLP: big = relu(s1@mW1+mb1); s3 = big@mW2+mb2 + s1; x = BN(s3)
        gemm(stream, s1, (const float*)d_in[16] + (long)l * 131072, (const float*)d_in[17] + l * 512, nullptr, big, NN, 256, 512, 1);
        gemm(stream, big, (const float*)d_in[18] + (long)l * 131072, (const float*)d_in[19] + l * 256, s1, s3, NN, 512, 256, 0);
        run_bn(stream, s3, part, stats, (const float*)d_in[24] + l * 256, (const float*)d_in[25] + l * 256, nullptr, x);
    }

    ln_kernel<<<NN, 256, 0, stream>>>(x, (const float*)d_in[26], (const float*)d_in[27], s1);
    pool_kernel<<<GG, 256, 0, stream>>>(s1, gf);

    // types_pred -> out[0 : N*100]
    gemm(stream, s1, (const float*)d_in[28], (const float*)d_in[29], nullptr, s2, NN, 256, 128, 2);
    gemm(stream, s2, (const float*)d_in[30], (const float*)d_in[31], nullptr, out, NN, 128, 100, 0);
    // lattice_pred -> out[N*100 : +G*9]
    gemm(stream, gf,  (const float*)d_in[32], (const float*)d_in[33], nullptr, l1b, GG, 256, 128, 2);
    gemm(stream, l1b, (const float*)d_in[34], (const float*)d_in[35], nullptr, l2b, GG, 128, 64, 2);
    gemm(stream, l2b, (const float*)d_in[36], nullptr, nullptr, out + (size_t)NN * 100, GG, 64, 9, 0);
    // frac_pred -> out[N*100+G*9 : ]
    gemm(stream, s1, (const float*)d_in[37], (const float*)d_in[38], nullptr, s2, NN, 256, 128, 2);
    gemm(stream, s2, (const float*)d_in[39], (const float*)d_in[40], nullptr, s3, NN, 128, 64, 2);
    gemm(stream, s3, (const float*)d_in[41], nullptr, nullptr, out + (size_t)NN * 100 + GG * 9, NN, 64, 3, 0);
}

// Round 11
// 1170.934 us; speedup vs baseline: 10.1715x; 1.2427x over previous
//
#include <hip/hip_runtime.h>
#include <hip/hip_bf16.h>
#include <math.h>

#define GG 256
#define NP 24
#define LL 3
#define CC 256
#define NN (GG*NP)   // 6144 nodes
#define HH 4
#define DH 64

typedef __hip_bfloat16 bf;
typedef __attribute__((ext_vector_type(8))) short bfrag;   // 8 bf16 (4 VGPR)
typedef __attribute__((ext_vector_type(4))) float ffrag;   // 4 fp32 acc

__device__ __forceinline__ short pk(float x) {
    union { bf h; short s; } u; u.h = __float2bfloat16(x); return u.s;
}

// ---------------------------------------------------------------------------
__global__ void detect_int_k(const unsigned int* __restrict__ at, int* flags) {
    __shared__ int ok;
    if (threadIdx.x == 0) ok = 1;
    __syncthreads();
    if (at[2 * threadIdx.x + 1] != 0u) ok = 0;   // benign race
    __syncthreads();
    if (threadIdx.x == 0) flags[0] = ok;
}

__global__ void signal_k(float* out, int n, float val) {
    int i = blockIdx.x * 256 + threadIdx.x;
    if (i < n) out[i] = val;
}

// ---------------------------------------------------------------------------
// Weight prep: fp32 [L][K][N] -> bf16 [L][N][K] (transpose + convert), once.
// ---------------------------------------------------------------------------
__global__ void transp(const float* __restrict__ src, bf* __restrict__ dst,
                       int K, int N) {
    long l = blockIdx.y;
    long sz = (long)K * N;
    int idx = blockIdx.x * 256 + threadIdx.x;
    if (idx >= sz) return;
    int k = idx / N, n = idx % N;
    dst[l * sz + (long)n * K + k] = __float2bfloat16(src[l * sz + idx]);
}

// ---------------------------------------------------------------------------
// A = [type_emb[atom_types] | time_emb]  (N x 512, fp32)
// ---------------------------------------------------------------------------
__global__ void build_A(const float* __restrict__ t, const float* __restrict__ type_emb,
                        const unsigned int* __restrict__ atoms,
                        float* __restrict__ A, const int* __restrict__ flags) {
    int i64 = flags[0];
    int idx = blockIdx.x * 256 + threadIdx.x;
    if (idx >= NN * 512) return;
    int n = idx >> 9;
    int k = idx & 511;
    if (k < 256) {
        int a = i64 ? (int)atoms[2 * n] : (int)atoms[n];
        A[idx] = type_emb[(long)a * CC + k];
    } else {
        int d = k - 256;
        int g = n / NP;
        float tv = t[g];
        int dd = (d < 128) ? d : d - 128;
        float tf = expf(dd * (-9.210340371976184f / 127.0f));
        float ang = tv * tf;
        A[idx] = (d < 128) ? sinf(ang) : cosf(ang);
    }
}

// ---------------------------------------------------------------------------
// MFMA bf16 GEMM: C[M,N] = epi(A[M,K] @ W + bias) (+res), W given as bf16
// W^T [N][K]. A fp32 (converted to bf16 during LDS staging), acc fp32.
// Block tile 64(M) x 128(N), 4 waves, wave tile 32x64 (2x4 16x16 mfma tiles).
// Requires M%64==0, N%128==0, K%32==0.
// Frag layouts (m89/m92-verified): A[m=lane&15][k=quad*8+j]; B = W^T rows,
// same pattern; D: col=lane&15 (n), row=quad*4+reg (m).
// ---------------------------------------------------------------------------
__global__ __launch_bounds__(256) void gemm_mfma(
        const float* __restrict__ A, const bf* __restrict__ Wt,
        const float* __restrict__ bias, const float* __restrict__ res,
        float* __restrict__ C, int M, int K, int N, int act) {
    __shared__ short As[64 * 40];    // bf16, row stride 40 (pad) -> 16B-aligned
    __shared__ short Bs[128 * 40];
    int tid = threadIdx.x;
    int lane = tid & 63, w = tid >> 6;
    int wm = w & 1, wn = w >> 1;
    int m0 = blockIdx.x * 64, n0 = blockIdx.y * 128;
    ffrag acc[2][4] = {};
    int sa_m = tid >> 2, sa_k = (tid & 3) << 3;   // A stage: 64 rows x 32 k
    int sb_n = tid >> 1, sb_k = (tid & 1) << 4;   // B stage: 128 rows x 32 k
    int fr_row = lane & 15, fr_k = (lane >> 4) << 3;

    for (int k0 = 0; k0 < K; k0 += 32) {
        const float* Ap = A + (long)(m0 + sa_m) * K + k0 + sa_k;
        float4 a1 = *(const float4*)Ap;
        float4 a2 = *(const float4*)(Ap + 4);
        const float4* Bp = (const float4*)(Wt + (long)(n0 + sb_n) * K + k0 + sb_k);
        float4 b1 = Bp[0], b2 = Bp[1];
        __syncthreads();   // previous tile's readers done
        bfrag av;
        av[0] = pk(a1.x); av[1] = pk(a1.y); av[2] = pk(a1.z); av[3] = pk(a1.w);
        av[4] = pk(a2.x); av[5] = pk(a2.y); av[6] = pk(a2.z); av[7] = pk(a2.w);
        *(bfrag*)(&As[sa_m * 40 + sa_k]) = av;
        *(float4*)(&Bs[sb_n * 40 + sb_k]) = b1;
        *(float4*)(&Bs[sb_n * 40 + sb_k + 8]) = b2;
        __syncthreads();
        bfrag af[2], bg[4];
#pragma unroll
        for (int mt = 0; mt < 2; ++mt)
            af[mt] = *(const bfrag*)(&As[(wm * 32 + mt * 16 + fr_row) * 40 + fr_k]);
#pragma unroll
        for (int nt = 0; nt < 4; ++nt)
            bg[nt] = *(const bfrag*)(&Bs[(wn * 64 + nt * 16 + fr_row) * 40 + fr_k]);
#pragma unroll
        for (int mt = 0; mt < 2; ++mt)
#pragma unroll
            for (int nt = 0; nt < 4; ++nt)
                acc[mt][nt] = __builtin_amdgcn_mfma_f32_16x16x32_bf16(
                    af[mt], bg[nt], acc[mt][nt], 0, 0, 0);
    }

    // epilogue: D col = lane&15 (n_local), row = (lane>>4)*4 + reg (m_local)
    int mbase = (lane >> 4) << 2;
#pragma unroll
    for (int mt = 0; mt < 2; ++mt) {
#pragma unroll
        for (int nt = 0; nt < 4; ++nt) {
            int n = n0 + wn * 64 + nt * 16 + (lane & 15);
            float bv = bias ? bias[n] : 0.f;
#pragma unroll
            for (int r = 0; r < 4; ++r) {
                int m = m0 + wm * 32 + mt * 16 + mbase + r;
                float v = acc[mt][nt][r] + bv;
                if (act == 1) v = fmaxf(v, 0.f);
                else if (act == 2) v = v / (1.f + expf(-v));
                if (res) v += res[(long)m * N + n];
                C[(long)m * N + n] = v;
            }
        }
    }
}

// ---------------------------------------------------------------------------
// fp32 tiled GEMM (for small/odd-N matrices). Unchanged from R9 (validated).
// ---------------------------------------------------------------------------
__global__ __launch_bounds__(256) void gemm_k(
        const float* __restrict__ A, const float* __restrict__ W,
        const float* __restrict__ bias, const float* __restrict__ res,
        float* __restrict__ Cf, int M, int K, int Nc, int act) {
    __shared__ __align__(16) float Asf[32][64];
    __shared__ __align__(16) float Bsf[32][64];
    int tid = threadIdx.x;
    int tx = tid & 15, ty = tid >> 4;
    int m0 = blockIdx.x * 64, n0 = blockIdx.y * 64;
    float acc[4][4] = {{0.f}};
    int am = tid >> 2;
    int ak = (tid & 3) << 3;
    int bk = tid >> 4;
    int bn = (tid & 15) << 2;

    for (int k0 = 0; k0 < K; k0 += 32) {
        const float* Ap = A + (long)(m0 + am) * K + k0 + ak;
        float4 a1 = *(const float4*)Ap;
        float4 a2 = *(const float4*)(Ap + 4);
        float w1[4], w2[4];
#pragma unroll
        for (int u = 0; u < 4; ++u) {
            int n = n0 + bn + u;
            w1[u] = (n < Nc) ? W[(long)(k0 + bk) * Nc + n] : 0.f;
            w2[u] = (n < Nc) ? W[(long)(k0 + bk + 16) * Nc + n] : 0.f;
        }
        __syncthreads();
        Asf[ak + 0][am] = a1.x; Asf[ak + 1][am] = a1.y;
        Asf[ak + 2][am] = a1.z; Asf[ak + 3][am] = a1.w;
        Asf[ak + 4][am] = a2.x; Asf[ak + 5][am] = a2.y;
        Asf[ak + 6][am] = a2.z; Asf[ak + 7][am] = a2.w;
#pragma unroll
        for (int u = 0; u < 4; ++u) {
            Bsf[bk][bn + u] = w1[u];
            Bsf[bk + 16][bn + u] = w2[u];
        }
        __syncthreads();
#pragma unroll
        for (int k = 0; k < 32; ++k) {
            float4 a = *(const float4*)(&Asf[k][ty << 2]);
            float4 b = *(const float4*)(&Bsf[k][tx << 2]);
            acc[0][0] += a.x * b.x; acc[0][1] += a.x * b.y; acc[0][2] += a.x * b.z; acc[0][3] += a.x * b.w;
            acc[1][0] += a.y * b.x; acc[1][1] += a.y * b.y; acc[1][2] += a.y * b.z; acc[1][3] += a.y * b.w;
            acc[2][0] += a.z * b.x; acc[2][1] += a.z * b.y; acc[2][2] += a.z * b.z; acc[2][3] += a.z * b.w;
            acc[3][0] += a.w * b.x; acc[3][1] += a.w * b.y; acc[3][2] += a.w * b.z; acc[3][3] += a.w * b.w;
        }
    }
#pragma unroll
    for (int i = 0; i < 4; ++i) {
        int m = m0 + (ty << 2) + i;
#pragma unroll
        for (int j = 0; j < 4; ++j) {
            int n = n0 + (tx << 2) + j;
            if (n >= Nc) continue;
            float v = acc[i][j];
            if (bias) v += bias[n];
            if (act == 1) v = fmaxf(v, 0.f);
            else if (act == 2) v = v / (1.f + expf(-v));
            if (res) v += res[(long)m * Nc + n];
            Cf[(long)m * Nc + n] = v;
        }
    }
}

// ---------------------------------------------------------------------------
// Fused GINEConv (R10 version, kept; ~138us/dispatch - next round's target).
// ---------------------------------------------------------------------------
__global__ __launch_bounds__(128, 2) void gine3(
        const float* __restrict__ x, const float* __restrict__ frac,
        const float* __restrict__ lattice, const float* __restrict__ geW,
        const float* __restrict__ geb, float* __restrict__ z, int l) {
    __shared__ __align__(16) float elds[6 * 24 * 60];
    __shared__ float fr[72];
    int tid = threadIdx.x;
    int g = blockIdx.x >> 2;
    int jq = blockIdx.x & 3;
    int c0 = tid, c1 = tid + 128;
    const float* Wg = geW + (long)l * 69 * CC;

    if (tid < 72) fr[tid] = frac[g * 72 + tid];
    __syncthreads();

    for (int item = tid; item < 6 * 24 * 30; item += 128) {
        int j = item / (24 * 30);
        int rem = item % (24 * 30);
        int i = rem / 30;
        int r = rem % 30;
        int d = r / 10, f = r % 10;
        int jn = jq * 6 + j;
        float fd = fr[jn * 3 + d] - fr[i * 3 + d];
        fd -= floorf(fd);
        float ang = 6.283185307179586f * (float)f * fd;
        elds[(j * 24 + i) * 60 + r] = sinf(ang);
        elds[(j * 24 + i) * 60 + 30 + r] = cosf(ang);
    }

    float4 W0[15], W1[15];
#pragma unroll
    for (int k4 = 0; k4 < 15; ++k4) {
        W0[k4] = make_float4(Wg[(k4 * 4 + 0) * CC + c0], Wg[(k4 * 4 + 1) * CC + c0],
                             Wg[(k4 * 4 + 2) * CC + c0], Wg[(k4 * 4 + 3) * CC + c0]);
        W1[k4] = make_float4(Wg[(k4 * 4 + 0) * CC + c1], Wg[(k4 * 4 + 1) * CC + c1],
                             Wg[(k4 * 4 + 2) * CC + c1], Wg[(k4 * 4 + 3) * CC + c1]);
    }
    float base0 = geb[(long)l * CC + c0];
    float base1 = geb[(long)l * CC + c1];
#pragma unroll
    for (int q = 0; q < 9; ++q) {
        float lv = lattice[(long)g * 9 + q];
        base0 += lv * Wg[(60 + q) * CC + c0];
        base1 += lv * Wg[(60 + q) * CC + c1];
    }
    float acc0[6] = {0.f, 0.f, 0.f, 0.f, 0.f, 0.f};
    float acc1[6] = {0.f, 0.f, 0.f, 0.f, 0.f, 0.f};
    __syncthreads();

    for (int i = 0; i < 24; ++i) {
        float t0 = x[(long)(g * NP + i) * CC + c0] + base0;
        float t1 = x[(long)(g * NP + i) * CC + c1] + base1;
#pragma unroll
        for (int j = 0; j < 6; ++j) {
            const float4* e4 = (const float4*)(elds + (j * 24 + i) * 60);
            float v0a = 0.f, v0b = 0.f, v1a = 0.f, v1b = 0.f;
#pragma unroll
            for (int k4 = 0; k4 < 15; k4 += 2) {
                float4 ea = e4[k4];
                v0a += ea.x * W0[k4].x; v0a += ea.y * W0[k4].y;
                v0a += ea.z * W0[k4].z; v0a += ea.w * W0[k4].w;
                v1a += ea.x * W1[k4].x; v1a += ea.y * W1[k4].y;
                v1a += ea.z * W1[k4].z; v1a += ea.w * W1[k4].w;
                if (k4 + 1 < 15) {
                    float4 eb = e4[k4 + 1];
                    v0b += eb.x * W0[k4 + 1].x; v0b += eb.y * W0[k4 + 1].y;
                    v0b += eb.z * W0[k4 + 1].z; v0b += eb.w * W0[k4 + 1].w;
                    v1b += eb.x * W1[k4 + 1].x; v1b += eb.y * W1[k4 + 1].y;
                    v1b += eb.z * W1[k4 + 1].z; v1b += eb.w * W1[k4 + 1].w;
                }
            }
            acc0[j] += fmaxf(t0 + (v0a + v0b), 0.f);
            acc1[j] += fmaxf(t1 + (v1a + v1b), 0.f);
        }
    }
#pragma unroll
    for (int j = 0; j < 6; ++j) {
        int node = g * NP + jq * 6 + j;
        z[(long)node * CC + c0] = x[(long)node * CC + c0] + acc0[j];
        z[(long)node * CC + c1] = x[(long)node * CC + c1] + acc1[j];
    }
}

// ---------------------------------------------------------------------------
__global__ void bn_stats1(const float* __restrict__ in, float* __restrict__ part) {
    int c = threadIdx.x, b = blockIdx.x;
    float s = 0.f, q = 0.f;
    for (int r = 0; r < 64; ++r) {
        float v = in[(long)(b * 64 + r) * CC + c];
        s += v; q += v * v;
    }
    part[b * 512 + c] = s;
    part[b * 512 + 256 + c] = q;
}
__global__ void bn_stats2(const float* __restrict__ part, float* __restrict__ stats) {
    int c = threadIdx.x;
    float s = 0.f, q = 0.f;
    for (int b = 0; b < 96; ++b) { s += part[b * 512 + c]; q += part[b * 512 + 256 + c]; }
    float m = s / (float)NN;
    float var = q / (float)NN - m * m;
    stats[c] = m;
    stats[256 + c] = rsqrtf(var + 1e-5f);
}
__global__ void bn_apply(const float* __restrict__ in, const float* __restrict__ stats,
                         const float* __restrict__ gma, const float* __restrict__ bta,
                         const float* __restrict__ add, float* __restrict__ out) {
    long idx = (long)blockIdx.x * 256 + threadIdx.x;
    int c = (int)(idx & 255);
    float v = (in[idx] - stats[c]) * stats[256 + c] * gma[c] + bta[c];
    if (add) v += add[idx];
    out[idx] = v;
}

// ---------------------------------------------------------------------------
// Attention v2 (validated R10).
// ---------------------------------------------------------------------------
__global__ __launch_bounds__(256, 2) void attn2(const float* __restrict__ qkv,
                                                float* __restrict__ o) {
    __shared__ __align__(16) float Kl[24 * 4 * 68];
    __shared__ __align__(16) float Vl[24 * 4 * 68];
    __shared__ float S[4 * 24 * 25];
    int tid = threadIdx.x, g = blockIdx.x;

    const float4* qkv4 = (const float4*)(qkv + (long)g * NP * 768);
    for (int idx = tid; idx < 24 * 128; idx += 256) {
        int row = idx >> 7;
        int c4 = idx & 127;
        int isV = c4 >> 6;
        int cc = c4 & 63;
        int h = cc >> 4, d4 = cc & 15;
        float4 val = qkv4[row * 192 + 64 + c4];
        float* dst = (isV ? Vl : Kl) + (row * 4 + h) * 68 + d4 * 4;
        *(float4*)dst = val;
    }
    __syncthreads();

    if (tid < 96) {
        int h = tid & 3, i = tid >> 2;
        const float4* qp = (const float4*)(qkv + ((long)(g * NP + i)) * 768 + h * 64);
        float4 q[16];
#pragma unroll
        for (int k = 0; k < 16; ++k) q[k] = qp[k];
        float sc[24];
        float mx = -1e30f;
        for (int j = 0; j < 24; ++j) {
            const float4* kp = (const float4*)(Kl + (j * 4 + h) * 68);
            float da = 0.f, db = 0.f;
#pragma unroll
            for (int k = 0; k < 16; k += 2) {
                float4 kv = kp[k];
                da += q[k].x * kv.x; da += q[k].y * kv.y;
                da += q[k].z * kv.z; da += q[k].w * kv.w;
                float4 kv2 = kp[k + 1];
                db += q[k + 1].x * kv2.x; db += q[k + 1].y * kv2.y;
                db += q[k + 1].z * kv2.z; db += q[k + 1].w * kv2.w;
            }
            float s = (da + db) * 0.125f;
            sc[j] = s;
            mx = fmaxf(mx, s);
        }
        float sum = 0.f;
#pragma unroll
        for (int j = 0; j < 24; ++j) { float p = expf(sc[j] - mx); sc[j] = p; sum += p; }
        float inv = 1.f / sum;
#pragma unroll
        for (int j = 0; j < 24; ++j) S[(h * 24 + i) * 25 + j] = sc[j] * inv;
    }
    __syncthreads();

    int h = tid >> 6, d = tid & 63;
    for (int i = 0; i < 24; ++i) {
        const float* Sp = S + (h * 24 + i) * 25;
        float a0 = 0.f, a1 = 0.f;
#pragma unroll
        for (int j = 0; j < 24; j += 2) {
            a0 += Sp[j] * Vl[(j * 4 + h) * 68 + d];
            a1 += Sp[j + 1] * Vl[((j + 1) * 4 + h) * 68 + d];
        }
        o[(long)(g * NP + i) * CC + h * 64 + d] = a0 + a1;
    }
}

// ---------------------------------------------------------------------------
__global__ __launch_bounds__(256) void ln_kernel(const float* __restrict__ x,
        const float* __restrict__ gma, const float* __restrict__ bta,
        float* __restrict__ out) {
    __shared__ float red[256];
    int n = blockIdx.x, c = threadIdx.x;
    float v = x[(long)n * CC + c];
    red[c] = v;
    __syncthreads();
    for (int s = 128; s > 0; s >>= 1) { if (c < s) red[c] += red[c + s]; __syncthreads(); }
    float m = red[0] * (1.f / 256.f);
    __syncthreads();
    float dv = v - m;
    red[c] = dv * dv;
    __syncthreads();
    for (int s = 128; s > 0; s >>= 1) { if (c < s) red[c] += red[c + s]; __syncthreads(); }
    float var = red[0] * (1.f / 256.f);
    out[(long)n * CC + c] = dv * rsqrtf(var + 1e-5f) * gma[c] + bta[c];
}

__global__ void pool_kernel(const float* __restrict__ hn, float* __restrict__ gf) {
    int g = blockIdx.x, c = threadIdx.x;
    float s = 0.f;
    for (int j = 0; j < NP; ++j) s += hn[(long)(g * NP + j) * CC + c];
    gf[g * CC + c] = s * (1.f / 24.f);
}

// ---------------------------------------------------------------------------
static void gemm(hipStream_t st, const float* A, const float* W, const float* bias,
                 const float* res, float* Cf, int M, int K, int Nc, int act) {
    dim3 grid(M / 64, (Nc + 63) / 64);
    gemm_k<<<grid, 256, 0, st>>>(A, W, bias, res, Cf, M, K, Nc, act);
}

static void gemmM(hipStream_t st, const float* A, const bf* Wt, const float* bias,
                  const float* res, float* Cf, int M, int K, int N, int act) {
    dim3 grid(M / 64, N / 128);
    gemm_mfma<<<grid, 256, 0, st>>>(A, Wt, bias, res, Cf, M, K, N, act);
}

static void run_bn(hipStream_t st, const float* in, float* part, float* stats,
                   const float* g_, const float* b_, const float* add, float* out) {
    bn_stats1<<<96, 256, 0, st>>>(in, part);
    bn_stats2<<<1, 256, 0, st>>>(part, stats);
    bn_apply<<<NN, 256, 0, st>>>(in, stats, g_, b_, add, out);
}

extern "C" void kernel_launch(void* const* d_in, const int* in_sizes, int n_in,
                              void* d_out, int out_size, void* d_ws, size_t ws_size,
                              hipStream_t stream) {
    float* out = (float*)d_out;
    int sigN = out_size < 256 ? out_size : 256;

    static const int EXP_SIZES[46] = {
        256, 18432, 2304, 25600, 131072, 256, 52992, 768, 196608, 768,
        196608, 768, 589824, 2304, 196608, 768, 393216, 1536, 393216, 768,
        768, 768, 768, 768, 768, 768, 256, 256, 32768, 128,
        12800, 100, 32768, 128, 8192, 64, 576, 32768, 128, 8192,
        64, 192, 6144, 6144, 147456, 147456 };
    if (n_in != 46) { signal_k<<<1, 256, 0, stream>>>(out, sigN, 3000.f + 8.f * n_in); return; }
    for (int i = 0; i < 46; ++i)
        if (in_sizes[i] != EXP_SIZES[i]) { signal_k<<<1, 256, 0, stream>>>(out, sigN, 512.f + 8.f * i); return; }
    if (out_size != NN * 100 + GG * 9 + NN * 3) { signal_k<<<1, 256, 0, stream>>>(out, sigN, 7777.f); return; }

    // ---- workspace ----
    char* base = (char*)d_ws;
    int* flags = (int*)base;                       // 256 B
    float* f32a = (float*)(base + 256);
    float* x  = f32a;                              // N*256
    float* s1 = x  + (size_t)NN * 256;             // N*256
    float* s2 = s1 + (size_t)NN * 256;             // N*256
    float* big = s2 + (size_t)NN * 256;            // N*768
    float* s3 = big + (size_t)NN * 512;            // alias of big's tail (lifetimes audited)
    float* part = big + (size_t)NN * 768;          // 96*512
    float* stats = part + 96 * 512;                // 512
    float* gf  = stats + 512;                      // G*256
    float* l1b = gf + GG * 256;                    // G*128
    float* l2b = l1b + GG * 128;                   // G*64
    bf* wt = (bf*)(l2b + GG * 64);                 // bf16 W^T mirrors, 2162688 elems
    // wt offsets (bf16 elems)
    const long O_NA = 0, O_G1 = 131072, O_G2 = 327680, O_AI = 524288,
               O_AO = 1114112, O_M1 = 1310720, O_M2 = 1703936,
               O_TRO = 2097152, O_FC = 2129920, WT_TOT = 2162688;
    size_t REQ = 256 + ((size_t)NN * 1536 + 96 * 512 + 512 + GG * 448) * 4 + WT_TOT * 2;
    if (ws_size < REQ) { signal_k<<<1, 256, 0, stream>>>(out, sigN, 9999.f); return; }

    const float* t       = (const float*)d_in[0];
    const float* frac    = (const float*)d_in[1];
    const float* lattice = (const float*)d_in[2];
    const float* type_emb = (const float*)d_in[3];

    detect_int_k<<<1, 256, 0, stream>>>((const unsigned int*)d_in[42], flags);

    // weight prep: fp32 [L][K][N] -> bf16 [L][N][K]
    transp<<<dim3((512 * 256 + 255) / 256, 1), 256, 0, stream>>>((const float*)d_in[4],  wt + O_NA, 512, 256);
    transp<<<dim3((256 * 256 + 255) / 256, 3), 256, 0, stream>>>((const float*)d_in[8],  wt + O_G1, 256, 256);
    transp<<<dim3((256 * 256 + 255) / 256, 3), 256, 0, stream>>>((const float*)d_in[10], wt + O_G2, 256, 256);
    transp<<<dim3((256 * 768 + 255) / 256, 3), 256, 0, stream>>>((const float*)d_in[12], wt + O_AI, 256, 768);
    transp<<<dim3((256 * 256 + 255) / 256, 3), 256, 0, stream>>>((const float*)d_in[14], wt + O_AO, 256, 256);
    transp<<<dim3((256 * 512 + 255) / 256, 3), 256, 0, stream>>>((const float*)d_in[16], wt + O_M1, 256, 512);
    transp<<<dim3((512 * 256 + 255) / 256, 3), 256, 0, stream>>>((const float*)d_in[18], wt + O_M2, 512, 256);
    transp<<<dim3((256 * 128 + 255) / 256, 1), 256, 0, stream>>>((const float*)d_in[28], wt + O_TRO, 256, 128);
    transp<<<dim3((256 * 128 + 255) / 256, 1), 256, 0, stream>>>((const float*)d_in[37], wt + O_FC, 256, 128);

    // x0 = concat(type_emb[atoms], time_emb) @ naW + nab
    build_A<<<(NN * 512 + 255) / 256, 256, 0, stream>>>(t, type_emb,
        (const unsigned int*)d_in[42], big, flags);
    gemmM(stream, big, wt + O_NA, (const float*)d_in[5], nullptr, x, NN, 512, 256, 0);

    for (int l = 0; l < LL; ++l) {
        // GINE: s1 = x + aggr
        gine3<<<GG * 4, 128, 0, stream>>>(x, frac, lattice,
            (const float*)d_in[6], (const float*)d_in[7], s1, l);
        // s2 = silu(s1@gW1+gb1); s3 = s2@gW2+gb2 + x; h1 = BN(s3) -> s2
        gemmM(stream, s1, wt + O_G1 + (long)l * 65536, (const float*)d_in[9]  + l * 256, nullptr, s2, NN, 256, 256, 2);
        gemmM(stream, s2, wt + O_G2 + (long)l * 65536, (const float*)d_in[11] + l * 256, x, s3, NN, 256, 256, 0);
        run_bn(stream, s3, part, stats, (const float*)d_in[20] + l * 256, (const float*)d_in[21] + l * 256, nullptr, s2);
        // attention: qkv=big; o=s1; s3 = s1@aoW+aob + x; s1 = h1 + BN(s3)
        gemmM(stream, x, wt + O_AI + (long)l * 196608, (const float*)d_in[13] + l * 768, nullptr, big, NN, 256, 768, 0);
        attn2<<<GG, 256, 0, stream>>>(big, s1);
        gemmM(stream, s1, wt + O_AO + (long)l * 65536, (const float*)d_in[15] + l * 256, x, s3, NN, 256, 256, 0);
        run_bn(stream, s3, part, stats, (const float*)d_in[22] + l * 256, (const float*)d_in[23] + l * 256, s2, s1);
        // MLP: big = relu(s1@mW1+mb1); s3 = big@mW2+mb2 + s1; x = BN(s3)
        gemmM(stream, s1, wt + O_M1 + (long)l * 131072, (const float*)d_in[17] + l * 512, nullptr, big, NN, 256, 512, 1);
        gemmM(stream, big, wt + O_M2 + (long)l * 131072, (const float*)d_in[19] + l * 256, s1, s3, NN, 512, 256, 0);
        run_bn(stream, s3, part, stats, (const float*)d_in[24] + l * 256, (const float*)d_in[25] + l * 256, nullptr, x);
    }

    ln_kernel<<<NN, 256, 0, stream>>>(x, (const float*)d_in[26], (const float*)d_in[27], s1);
    pool_kernel<<<GG, 256, 0, stream>>>(s1, gf);

    // types_pred -> out[0 : N*100]
    gemmM(stream, s1, wt + O_TRO, (const float*)d_in[29], nullptr, s2, NN, 256, 128, 2);
    gemm(stream, s2, (const float*)d_in[30], (const float*)d_in[31], nullptr, out, NN, 128, 100, 0);
    // lattice_pred -> out[N*100 : +G*9]
    gemm(stream, gf,  (const float*)d_in[32], (const float*)d_in[33], nullptr, l1b, GG, 256, 128, 2);
    gemm(stream, l1b, (const float*)d_in[34], (const float*)d_in[35], nullptr, l2b, GG, 128, 64, 2);
    gemm(stream, l2b, (const float*)d_in[36], nullptr, nullptr, out + (size_t)NN * 100, GG, 64, 9, 0);
    // frac_pred -> out[N*100+G*9 : ]
    gemmM(stream, s1, wt + O_FC, (const float*)d_in[38], nullptr, s2, NN, 256, 128, 2);
    gemm(stream, s2, (const float*)d_in[39], (const float*)d_in[40], nullptr, s3, NN, 128, 64, 2);
    gemm(stream, s3, (const float*)d_in[41], nullptr, nullptr, out + (size_t)NN * 100 + GG * 9, NN, 64, 3, 0);
}

// Round 13
// 1013.981 us; speedup vs baseline: 11.7459x; 1.1548x over previous
//
#include <hip/hip_runtime.h>
#include <hip/hip_bf16.h>
#include <math.h>

#define GG 256
#define NP 24
#define LL 3
#define CC 256
#define NN (GG*NP)   // 6144 nodes
#define HH 4
#define DH 64

typedef __hip_bfloat16 bf;
typedef __attribute__((ext_vector_type(8))) short bfrag;   // 8 bf16 (4 VGPR)
typedef __attribute__((ext_vector_type(4))) float ffrag;   // 4 fp32 acc

__device__ __forceinline__ short pk(float x) {
    union { bf h; short s; } u; u.h = __float2bfloat16(x); return u.s;
}
__device__ __forceinline__ float b2f_s(short x) {
    union { short s; bf h; } u; u.s = x; return __bfloat162float(u.h);
}

// ---------------------------------------------------------------------------
__global__ void detect_int_k(const unsigned int* __restrict__ at, int* flags) {
    __shared__ int ok;
    if (threadIdx.x == 0) ok = 1;
    __syncthreads();
    if (at[2 * threadIdx.x + 1] != 0u) ok = 0;   // benign race
    __syncthreads();
    if (threadIdx.x == 0) flags[0] = ok;
}

__global__ void signal_k(float* out, int n, float val) {
    int i = blockIdx.x * 256 + threadIdx.x;
    if (i < n) out[i] = val;
}

// ---------------------------------------------------------------------------
// Weight prep: fp32 [L][K][N] -> bf16 [L][N][K] (transpose + convert), once.
// ---------------------------------------------------------------------------
__global__ void transp(const float* __restrict__ src, bf* __restrict__ dst,
                       int K, int N) {
    long l = blockIdx.y;
    long sz = (long)K * N;
    int idx = blockIdx.x * 256 + threadIdx.x;
    if (idx >= sz) return;
    int k = idx / N, n = idx % N;
    dst[l * sz + (long)n * K + k] = __float2bfloat16(src[l * sz + idx]);
}

// ---------------------------------------------------------------------------
// GINE edge-weight prep: geW fp32 [L][69][256] -> split bf16 W^T
// [L][half][n 0..127][k 0..63] (k<60 real, else 0), hi and lo parts.
// ---------------------------------------------------------------------------
__global__ void prep_gew(const float* __restrict__ geW, short* __restrict__ wh,
                         short* __restrict__ wl) {
    int idx = blockIdx.x * 256 + threadIdx.x;   // 3*2*128*64 = 49152
    if (idx >= 49152) return;
    int k = idx & 63;
    int n = (idx >> 6) & 127;
    int half = (idx >> 13) & 1;
    int l = idx >> 14;
    float v = (k < 60) ? geW[(long)l * 69 * 256 + (long)k * 256 + half * 128 + n] : 0.f;
    short hi = pk(v);
    short lo = pk(v - b2f_s(hi));
    wh[idx] = hi;
    wl[idx] = lo;
}

// ---------------------------------------------------------------------------
// A = [type_emb[atom_types] | time_emb]  (N x 512, fp32)
// ---------------------------------------------------------------------------
__global__ void build_A(const float* __restrict__ t, const float* __restrict__ type_emb,
                        const unsigned int* __restrict__ atoms,
                        float* __restrict__ A, const int* __restrict__ flags) {
    int i64 = flags[0];
    int idx = blockIdx.x * 256 + threadIdx.x;
    if (idx >= NN * 512) return;
    int n = idx >> 9;
    int k = idx & 511;
    if (k < 256) {
        int a = i64 ? (int)atoms[2 * n] : (int)atoms[n];
        A[idx] = type_emb[(long)a * CC + k];
    } else {
        int d = k - 256;
        int g = n / NP;
        float tv = t[g];
        int dd = (d < 128) ? d : d - 128;
        float tf = expf(dd * (-9.210340371976184f / 127.0f));
        float ang = tv * tf;
        A[idx] = (d < 128) ? sinf(ang) : cosf(ang);
    }
}

// ---------------------------------------------------------------------------
// MFMA bf16 GEMM (validated R11). C = epi(A@W + bias) (+res), Wt = bf16 W^T.
// ---------------------------------------------------------------------------
__global__ __launch_bounds__(256) void gemm_mfma(
        const float* __restrict__ A, const bf* __restrict__ Wt,
        const float* __restrict__ bias, const float* __restrict__ res,
        float* __restrict__ C, int M, int K, int N, int act) {
    __shared__ short As[64 * 40];
    __shared__ short Bs[128 * 40];
    int tid = threadIdx.x;
    int lane = tid & 63, w = tid >> 6;
    int wm = w & 1, wn = w >> 1;
    int m0 = blockIdx.x * 64, n0 = blockIdx.y * 128;
    ffrag acc[2][4] = {};
    int sa_m = tid >> 2, sa_k = (tid & 3) << 3;
    int sb_n = tid >> 1, sb_k = (tid & 1) << 4;
    int fr_row = lane & 15, fr_k = (lane >> 4) << 3;

    for (int k0 = 0; k0 < K; k0 += 32) {
        const float* Ap = A + (long)(m0 + sa_m) * K + k0 + sa_k;
        float4 a1 = *(const float4*)Ap;
        float4 a2 = *(const float4*)(Ap + 4);
        const float4* Bp = (const float4*)(Wt + (long)(n0 + sb_n) * K + k0 + sb_k);
        float4 b1 = Bp[0], b2 = Bp[1];
        __syncthreads();
        bfrag av;
        av[0] = pk(a1.x); av[1] = pk(a1.y); av[2] = pk(a1.z); av[3] = pk(a1.w);
        av[4] = pk(a2.x); av[5] = pk(a2.y); av[6] = pk(a2.z); av[7] = pk(a2.w);
        *(bfrag*)(&As[sa_m * 40 + sa_k]) = av;
        *(float4*)(&Bs[sb_n * 40 + sb_k]) = b1;
        *(float4*)(&Bs[sb_n * 40 + sb_k + 8]) = b2;
        __syncthreads();
        bfrag af[2], bg[4];
#pragma unroll
        for (int mt = 0; mt < 2; ++mt)
            af[mt] = *(const bfrag*)(&As[(wm * 32 + mt * 16 + fr_row) * 40 + fr_k]);
#pragma unroll
        for (int nt = 0; nt < 4; ++nt)
            bg[nt] = *(const bfrag*)(&Bs[(wn * 64 + nt * 16 + fr_row) * 40 + fr_k]);
#pragma unroll
        for (int mt = 0; mt < 2; ++mt)
#pragma unroll
            for (int nt = 0; nt < 4; ++nt)
                acc[mt][nt] = __builtin_amdgcn_mfma_f32_16x16x32_bf16(
                    af[mt], bg[nt], acc[mt][nt], 0, 0, 0);
    }

    int mbase = (lane >> 4) << 2;
#pragma unroll
    for (int mt = 0; mt < 2; ++mt) {
#pragma unroll
        for (int nt = 0; nt < 4; ++nt) {
            int n = n0 + wn * 64 + nt * 16 + (lane & 15);
            float bv = bias ? bias[n] : 0.f;
#pragma unroll
            for (int r = 0; r < 4; ++r) {
                int m = m0 + wm * 32 + mt * 16 + mbase + r;
                float v = acc[mt][nt][r] + bv;
                if (act == 1) v = fmaxf(v, 0.f);
                else if (act == 2) v = v / (1.f + expf(-v));
                if (res) v += res[(long)m * N + n];
                C[(long)m * N + n] = v;
            }
        }
    }
}

// ---------------------------------------------------------------------------
// fp32 tiled GEMM (small/odd-N). Validated R9-R11.
// ---------------------------------------------------------------------------
__global__ __launch_bounds__(256) void gemm_k(
        const float* __restrict__ A, const float* __restrict__ W,
        const float* __restrict__ bias, const float* __restrict__ res,
        float* __restrict__ Cf, int M, int K, int Nc, int act) {
    __shared__ __align__(16) float Asf[32][64];
    __shared__ __align__(16) float Bsf[32][64];
    int tid = threadIdx.x;
    int tx = tid & 15, ty = tid >> 4;
    int m0 = blockIdx.x * 64, n0 = blockIdx.y * 64;
    float acc[4][4] = {{0.f}};
    int am = tid >> 2;
    int ak = (tid & 3) << 3;
    int bk = tid >> 4;
    int bn = (tid & 15) << 2;

    for (int k0 = 0; k0 < K; k0 += 32) {
        const float* Ap = A + (long)(m0 + am) * K + k0 + ak;
        float4 a1 = *(const float4*)Ap;
        float4 a2 = *(const float4*)(Ap + 4);
        float w1[4], w2[4];
#pragma unroll
        for (int u = 0; u < 4; ++u) {
            int n = n0 + bn + u;
            w1[u] = (n < Nc) ? W[(long)(k0 + bk) * Nc + n] : 0.f;
            w2[u] = (n < Nc) ? W[(long)(k0 + bk + 16) * Nc + n] : 0.f;
        }
        __syncthreads();
        Asf[ak + 0][am] = a1.x; Asf[ak + 1][am] = a1.y;
        Asf[ak + 2][am] = a1.z; Asf[ak + 3][am] = a1.w;
        Asf[ak + 4][am] = a2.x; Asf[ak + 5][am] = a2.y;
        Asf[ak + 6][am] = a2.z; Asf[ak + 7][am] = a2.w;
#pragma unroll
        for (int u = 0; u < 4; ++u) {
            Bsf[bk][bn + u] = w1[u];
            Bsf[bk + 16][bn + u] = w2[u];
        }
        __syncthreads();
#pragma unroll
        for (int k = 0; k < 32; ++k) {
            float4 a = *(const float4*)(&Asf[k][ty << 2]);
            float4 b = *(const float4*)(&Bsf[k][tx << 2]);
            acc[0][0] += a.x * b.x; acc[0][1] += a.x * b.y; acc[0][2] += a.x * b.z; acc[0][3] += a.x * b.w;
            acc[1][0] += a.y * b.x; acc[1][1] += a.y * b.y; acc[1][2] += a.y * b.z; acc[1][3] += a.y * b.w;
            acc[2][0] += a.z * b.x; acc[2][1] += a.z * b.y; acc[2][2] += a.z * b.z; acc[2][3] += a.z * b.w;
            acc[3][0] += a.w * b.x; acc[3][1] += a.w * b.y; acc[3][2] += a.w * b.z; acc[3][3] += a.w * b.w;
        }
    }
#pragma unroll
    for (int i = 0; i < 4; ++i) {
        int m = m0 + (ty << 2) + i;
#pragma unroll
        for (int j = 0; j < 4; ++j) {
            int n = n0 + (tx << 2) + j;
            if (n >= Nc) continue;
            float v = acc[i][j];
            if (bias) v += bias[n];
            if (act == 1) v = fmaxf(v, 0.f);
            else if (act == 2) v = v / (1.f + expf(-v));
            if (res) v += res[(long)m * Nc + n];
            Cf[(long)m * Nc + n] = v;
        }
    }
}

// ---------------------------------------------------------------------------
// GINE v5 — MFMA with split-bf16 (numerics ~= fp32). FIXED R13: W^T LDS
// staging now copies all 32 u32 per row (R12 copied only 16 -> half of
// Wh/Wl was uninitialized LDS -> NaN).
// Block = (graph g, N-half). 512 blocks x 256 thr (4 waves), 2 blocks/CU.
// ---------------------------------------------------------------------------
__global__ __launch_bounds__(256, 2) void gine4(
        const float* __restrict__ x, const float* __restrict__ frac,
        const float* __restrict__ lattice, const float* __restrict__ geW,
        const float* __restrict__ geb, const short* __restrict__ gewt_h,
        const short* __restrict__ gewt_l, float* __restrict__ z, int l) {
    __shared__ __align__(16) short Wh[128 * 72];   // 18432 B
    __shared__ __align__(16) short Wl[128 * 72];   // 18432 B
    __shared__ __align__(16) short Eh[32 * 72];    // 4608 B
    __shared__ __align__(16) short El[32 * 72];    // 4608 B
    __shared__ float xls[24 * 132];                // 12672 B
    __shared__ float basel[128];                   // 512 B
    __shared__ float fr[72];                       // 288 B   (total ~58.2 KB)

    int tid = threadIdx.x;
    int lane = tid & 63, w = tid >> 6, quad = lane >> 4, l16 = lane & 15;
    int g = blockIdx.x >> 1, half = blockIdx.x & 1;

    // ---- stage W^T hi/lo: global [l][half][n][64] shorts -> LDS stride 72 ----
    {
        const unsigned int* gh = (const unsigned int*)gewt_h;
        const unsigned int* gl = (const unsigned int*)gewt_l;
        unsigned int* lh = (unsigned int*)Wh;
        unsigned int* ll = (unsigned int*)Wl;
        int base = (l * 2 + half) * 4096;   // u32 units (128 rows * 32 u32)
        for (int idx = tid; idx < 4096; idx += 256) {
            int row = idx >> 5, c = idx & 31;   // 32 u32 = 64 shorts per row
            lh[row * 36 + c] = gh[base + idx];
            ll[row * 36 + c] = gl[base + idx];
        }
    }
    // ---- stage x half, frac, base ----
    for (int idx = tid; idx < 24 * 128; idx += 256) {
        int i = idx >> 7, cl = idx & 127;
        xls[i * 132 + cl] = x[(long)(g * NP + i) * CC + half * 128 + cl];
    }
    if (tid < 72) fr[tid] = frac[g * 72 + tid];
    if (tid < 128) {
        int cg = half * 128 + tid;
        float bv = geb[(long)l * CC + cg];
#pragma unroll
        for (int q = 0; q < 9; ++q)
            bv += lattice[(long)g * 9 + q] * geW[(long)l * 69 * 256 + (long)(60 + q) * 256 + cg];
        basel[tid] = bv;
    }
    __syncthreads();

    // ---- preload B fragments (loop-invariant): [nt][ks] hi/lo ----
    bfrag bh[2][2], bl[2][2];
#pragma unroll
    for (int nt = 0; nt < 2; ++nt) {
        int nrow = w * 32 + nt * 16 + l16;
#pragma unroll
        for (int ks = 0; ks < 2; ++ks) {
            bh[nt][ks] = *(const bfrag*)(&Wh[nrow * 72 + ks * 32 + quad * 8]);
            bl[nt][ks] = *(const bfrag*)(&Wl[nrow * 72 + ks * 32 + quad * 8]);
        }
    }
    float bse[2];
#pragma unroll
    for (int nt = 0; nt < 2; ++nt) bse[nt] = basel[w * 32 + nt * 16 + l16];

    // ---- chunk loop over dst j ----
    for (int j = 0; j < 24; ++j) {
        // build E (i 0..31 x k 0..63); i>=24 or k>=60 -> 0
        for (int idx = tid; idx < 2048; idx += 256) {
            int i = idx >> 6, k = idx & 63;
            float val = 0.f;
            if (i < 24 && k < 60) {
                int r = (k < 30) ? k : k - 30;
                int d = r / 10, f = r % 10;
                float fd = fr[j * 3 + d] - fr[i * 3 + d];
                fd -= floorf(fd);
                float ang = 6.283185307179586f * (float)f * fd;
                val = (k < 30) ? sinf(ang) : cosf(ang);
            }
            short hi = pk(val);
            Eh[i * 72 + k] = hi;
            El[i * 72 + k] = pk(val - b2f_s(hi));
        }
        __syncthreads();

        ffrag acc[2][2] = {};   // [mt][nt]
#pragma unroll
        for (int mt = 0; mt < 2; ++mt) {
            int row = mt * 16 + l16;
#pragma unroll
            for (int ks = 0; ks < 2; ++ks) {
                bfrag ah = *(const bfrag*)(&Eh[row * 72 + ks * 32 + quad * 8]);
                bfrag al = *(const bfrag*)(&El[row * 72 + ks * 32 + quad * 8]);
#pragma unroll
                for (int nt = 0; nt < 2; ++nt) {
                    acc[mt][nt] = __builtin_amdgcn_mfma_f32_16x16x32_bf16(ah, bh[nt][ks], acc[mt][nt], 0, 0, 0);
                    acc[mt][nt] = __builtin_amdgcn_mfma_f32_16x16x32_bf16(ah, bl[nt][ks], acc[mt][nt], 0, 0, 0);
                    acc[mt][nt] = __builtin_amdgcn_mfma_f32_16x16x32_bf16(al, bh[nt][ks], acc[mt][nt], 0, 0, 0);
                }
            }
        }

        // epilogue: relu + reduce over i (rows), write z[g*24+j][cg]
#pragma unroll
        for (int nt = 0; nt < 2; ++nt) {
            int cl = w * 32 + nt * 16 + l16;
            float part = 0.f;
#pragma unroll
            for (int mt = 0; mt < 2; ++mt) {
                int ibase = mt * 16 + quad * 4;
                if (ibase < 24) {
#pragma unroll
                    for (int r = 0; r < 4; ++r) {
                        float xv = xls[(ibase + r) * 132 + cl];
                        part += fmaxf(xv + bse[nt] + acc[mt][nt][r], 0.f);
                    }
                }
            }
            part += __shfl_xor(part, 16);
            part += __shfl_xor(part, 32);
            if (lane < 16)
                z[(long)(g * NP + j) * CC + half * 128 + cl] = xls[j * 132 + cl] + part;
        }
        __syncthreads();   // protect E before next chunk's writes
    }
}

// ---------------------------------------------------------------------------
__global__ void bn_stats1(const float* __restrict__ in, float* __restrict__ part) {
    int c = threadIdx.x, b = blockIdx.x;
    float s = 0.f, q = 0.f;
    for (int r = 0; r < 64; ++r) {
        float v = in[(long)(b * 64 + r) * CC + c];
        s += v; q += v * v;
    }
    part[b * 512 + c] = s;
    part[b * 512 + 256 + c] = q;
}
__global__ void bn_stats2(const float* __restrict__ part, float* __restrict__ stats) {
    int c = threadIdx.x;
    float s = 0.f, q = 0.f;
    for (int b = 0; b < 96; ++b) { s += part[b * 512 + c]; q += part[b * 512 + 256 + c]; }
    float m = s / (float)NN;
    float var = q / (float)NN - m * m;
    stats[c] = m;
    stats[256 + c] = rsqrtf(var + 1e-5f);
}
__global__ void bn_apply(const float* __restrict__ in, const float* __restrict__ stats,
                         const float* __restrict__ gma, const float* __restrict__ bta,
                         const float* __restrict__ add, float* __restrict__ out) {
    long idx = (long)blockIdx.x * 256 + threadIdx.x;
    int c = (int)(idx & 255);
    float v = (in[idx] - stats[c]) * stats[256 + c] * gma[c] + bta[c];
    if (add) v += add[idx];
    out[idx] = v;
}

// ---------------------------------------------------------------------------
// Attention v2 (validated R10).
// ---------------------------------------------------------------------------
__global__ __launch_bounds__(256, 2) void attn2(const float* __restrict__ qkv,
                                                float* __restrict__ o) {
    __shared__ __align__(16) float Kl[24 * 4 * 68];
    __shared__ __align__(16) float Vl[24 * 4 * 68];
    __shared__ float S[4 * 24 * 25];
    int tid = threadIdx.x, g = blockIdx.x;

    const float4* qkv4 = (const float4*)(qkv + (long)g * NP * 768);
    for (int idx = tid; idx < 24 * 128; idx += 256) {
        int row = idx >> 7;
        int c4 = idx & 127;
        int isV = c4 >> 6;
        int cc = c4 & 63;
        int h = cc >> 4, d4 = cc & 15;
        float4 val = qkv4[row * 192 + 64 + c4];
        float* dst = (isV ? Vl : Kl) + (row * 4 + h) * 68 + d4 * 4;
        *(float4*)dst = val;
    }
    __syncthreads();

    if (tid < 96) {
        int h = tid & 3, i = tid >> 2;
        const float4* qp = (const float4*)(qkv + ((long)(g * NP + i)) * 768 + h * 64);
        float4 q[16];
#pragma unroll
        for (int k = 0; k < 16; ++k) q[k] = qp[k];
        float sc[24];
        float mx = -1e30f;
        for (int j = 0; j < 24; ++j) {
            const float4* kp = (const float4*)(Kl + (j * 4 + h) * 68);
            float da = 0.f, db = 0.f;
#pragma unroll
            for (int k = 0; k < 16; k += 2) {
                float4 kv = kp[k];
                da += q[k].x * kv.x; da += q[k].y * kv.y;
                da += q[k].z * kv.z; da += q[k].w * kv.w;
                float4 kv2 = kp[k + 1];
                db += q[k + 1].x * kv2.x; db += q[k + 1].y * kv2.y;
                db += q[k + 1].z * kv2.z; db += q[k + 1].w * kv2.w;
            }
            float s = (da + db) * 0.125f;
            sc[j] = s;
            mx = fmaxf(mx, s);
        }
        float sum = 0.f;
#pragma unroll
        for (int j = 0; j < 24; ++j) { float p = expf(sc[j] - mx); sc[j] = p; sum += p; }
        float inv = 1.f / sum;
#pragma unroll
        for (int j = 0; j < 24; ++j) S[(h * 24 + i) * 25 + j] = sc[j] * inv;
    }
    __syncthreads();

    int h = tid >> 6, d = tid & 63;
    for (int i = 0; i < 24; ++i) {
        const float* Sp = S + (h * 24 + i) * 25;
        float a0 = 0.f, a1 = 0.f;
#pragma unroll
        for (int j = 0; j < 24; j += 2) {
            a0 += Sp[j] * Vl[(j * 4 + h) * 68 + d];
            a1 += Sp[j + 1] * Vl[((j + 1) * 4 + h) * 68 + d];
        }
        o[(long)(g * NP + i) * CC + h * 64 + d] = a0 + a1;
    }
}

// ---------------------------------------------------------------------------
__global__ __launch_bounds__(256) void ln_kernel(const float* __restrict__ x,
        const float* __restrict__ gma, const float* __restrict__ bta,
        float* __restrict__ out) {
    __shared__ float red[256];
    int n = blockIdx.x, c = threadIdx.x;
    float v = x[(long)n * CC + c];
    red[c] = v;
    __syncthreads();
    for (int s = 128; s > 0; s >>= 1) { if (c < s) red[c] += red[c + s]; __syncthreads(); }
    float m = red[0] * (1.f / 256.f);
    __syncthreads();
    float dv = v - m;
    red[c] = dv * dv;
    __syncthreads();
    for (int s = 128; s > 0; s >>= 1) { if (c < s) red[c] += red[c + s]; __syncthreads(); }
    float var = red[0] * (1.f / 256.f);
    out[(long)n * CC + c] = dv * rsqrtf(var + 1e-5f) * gma[c] + bta[c];
}

__global__ void pool_kernel(const float* __restrict__ hn, float* __restrict__ gf) {
    int g = blockIdx.x, c = threadIdx.x;
    float s = 0.f;
    for (int j = 0; j < NP; ++j) s += hn[(long)(g * NP + j) * CC + c];
    gf[g * CC + c] = s * (1.f / 24.f);
}

// ---------------------------------------------------------------------------
static void gemm(hipStream_t st, const float* A, const float* W, const float* bias,
                 const float* res, float* Cf, int M, int K, int Nc, int act) {
    dim3 grid(M / 64, (Nc + 63) / 64);
    gemm_k<<<grid, 256, 0, st>>>(A, W, bias, res, Cf, M, K, Nc, act);
}

static void gemmM(hipStream_t st, const float* A, const bf* Wt, const float* bias,
                  const float* res, float* Cf, int M, int K, int N, int act) {
    dim3 grid(M / 64, N / 128);
    gemm_mfma<<<grid, 256, 0, st>>>(A, Wt, bias, res, Cf, M, K, N, act);
}

static void run_bn(hipStream_t st, const float* in, float* part, float* stats,
                   const float* g_, const float* b_, const float* add, float* out) {
    bn_stats1<<<96, 256, 0, st>>>(in, part);
    bn_stats2<<<1, 256, 0, st>>>(part, stats);
    bn_apply<<<NN, 256, 0, st>>>(in, stats, g_, b_, add, out);
}

extern "C" void kernel_launch(void* const* d_in, const int* in_sizes, int n_in,
                              void* d_out, int out_size, void* d_ws, size_t ws_size,
                              hipStream_t stream) {
    float* out = (float*)d_out;
    int sigN = out_size < 256 ? out_size : 256;

    static const int EXP_SIZES[46] = {
        256, 18432, 2304, 25600, 131072, 256, 52992, 768, 196608, 768,
        196608, 768, 589824, 2304, 196608, 768, 393216, 1536, 393216, 768,
        768, 768, 768, 768, 768, 768, 256, 256, 32768, 128,
        12800, 100, 32768, 128, 8192, 64, 576, 32768, 128, 8192,
        64, 192, 6144, 6144, 147456, 147456 };
    if (n_in != 46) { signal_k<<<1, 256, 0, stream>>>(out, sigN, 3000.f + 8.f * n_in); return; }
    for (int i = 0; i < 46; ++i)
        if (in_sizes[i] != EXP_SIZES[i]) { signal_k<<<1, 256, 0, stream>>>(out, sigN, 512.f + 8.f * i); return; }
    if (out_size != NN * 100 + GG * 9 + NN * 3) { signal_k<<<1, 256, 0, stream>>>(out, sigN, 7777.f); return; }

    // ---- workspace ----
    char* base = (char*)d_ws;
    int* flags = (int*)base;                       // 256 B
    float* f32a = (float*)(base + 256);
    float* x  = f32a;                              // N*256
    float* s1 = x  + (size_t)NN * 256;             // N*256
    float* s2 = s1 + (size_t)NN * 256;             // N*256
    float* big = s2 + (size_t)NN * 256;            // N*768
    float* s3 = big + (size_t)NN * 512;            // alias of big's tail (lifetimes audited)
    float* part = big + (size_t)NN * 768;          // 96*512
    float* stats = part + 96 * 512;                // 512
    float* gf  = stats + 512;                      // G*256
    float* l1b = gf + GG * 256;                    // G*128
    float* l2b = l1b + GG * 128;                   // G*64
    bf* wt = (bf*)(l2b + GG * 64);                 // bf16 W^T mirrors
    const long O_NA = 0, O_G1 = 131072, O_G2 = 327680, O_AI = 524288,
               O_AO = 1114112, O_M1 = 1310720, O_M2 = 1703936,
               O_TRO = 2097152, O_FC = 2129920, WT_TOT = 2162688;
    short* gewt_h = (short*)(wt + WT_TOT);         // 49152 shorts
    short* gewt_l = gewt_h + 49152;                // 49152 shorts
    size_t REQ = 256 + ((size_t)NN * 1536 + 96 * 512 + 512 + GG * 448) * 4
               + WT_TOT * 2 + 49152 * 2 * 2;
    if (ws_size < REQ) { signal_k<<<1, 256, 0, stream>>>(out, sigN, 9999.f); return; }

    const float* t       = (const float*)d_in[0];
    const float* frac    = (const float*)d_in[1];
    const float* lattice = (const float*)d_in[2];
    const float* type_emb = (const float*)d_in[3];

    detect_int_k<<<1, 256, 0, stream>>>((const unsigned int*)d_in[42], flags);

    // weight prep
    transp<<<dim3((512 * 256 + 255) / 256, 1), 256, 0, stream>>>((const float*)d_in[4],  wt + O_NA, 512, 256);
    transp<<<dim3((256 * 256 + 255) / 256, 3), 256, 0, stream>>>((const float*)d_in[8],  wt + O_G1, 256, 256);
    transp<<<dim3((256 * 256 + 255) / 256, 3), 256, 0, stream>>>((const float*)d_in[10], wt + O_G2, 256, 256);
    transp<<<dim3((256 * 768 + 255) / 256, 3), 256, 0, stream>>>((const float*)d_in[12], wt + O_AI, 256, 768);
    transp<<<dim3((256 * 256 + 255) / 256, 3), 256, 0, stream>>>((const float*)d_in[14], wt + O_AO, 256, 256);
    transp<<<dim3((256 * 512 + 255) / 256, 3), 256, 0, stream>>>((const float*)d_in[16], wt + O_M1, 256, 512);
    transp<<<dim3((512 * 256 + 255) / 256, 3), 256, 0, stream>>>((const float*)d_in[18], wt + O_M2, 512, 256);
    transp<<<dim3((256 * 128 + 255) / 256, 1), 256, 0, stream>>>((const float*)d_in[28], wt + O_TRO, 256, 128);
    transp<<<dim3((256 * 128 + 255) / 256, 1), 256, 0, stream>>>((const float*)d_in[37], wt + O_FC, 256, 128);
    prep_gew<<<192, 256, 0, stream>>>((const float*)d_in[6], gewt_h, gewt_l);

    // x0 = concat(type_emb[atoms], time_emb) @ naW + nab
    build_A<<<(NN * 512 + 255) / 256, 256, 0, stream>>>(t, type_emb,
        (const unsigned int*)d_in[42], big, flags);
    gemmM(stream, big, wt + O_NA, (const float*)d_in[5], nullptr, x, NN, 512, 256, 0);

    for (int l = 0; l < LL; ++l) {
        // GINE: s1 = x + aggr (MFMA split-bf16)
        gine4<<<GG * 2, 256, 0, stream>>>(x, frac, lattice,
            (const float*)d_in[6], (const float*)d_in[7], gewt_h, gewt_l, s1, l);
        // s2 = silu(s1@gW1+gb1); s3 = s2@gW2+gb2 + x; h1 = BN(s3) -> s2
        gemmM(stream, s1, wt + O_G1 + (long)l * 65536, (const float*)d_in[9]  + l * 256, nullptr, s2, NN, 256, 256, 2);
        gemmM(stream, s2, wt + O_G2 + (long)l * 65536, (const float*)d_in[11] + l * 256, x, s3, NN, 256, 256, 0);
        run_bn(stream, s3, part, stats, (const float*)d_in[20] + l * 256, (const float*)d_in[21] + l * 256, nullptr, s2);
        // attention: qkv=big; o=s1; s3 = s1@aoW+aob + x; s1 = h1 + BN(s3)
        gemmM(stream, x, wt + O_AI + (long)l * 196608, (const float*)d_in[13] + l * 768, nullptr, big, NN, 256, 768, 0);
        attn2<<<GG, 256, 0, stream>>>(big, s1);
        gemmM(stream, s1, wt + O_AO + (long)l * 65536, (const float*)d_in[15] + l * 256, x, s3, NN, 256, 256, 0);
        run_bn(stream, s3, part, stats, (const float*)d_in[22] + l * 256, (const float*)d_in[23] + l * 256, s2, s1);
        // MLP: big = relu(s1@mW1+mb1); s3 = big@mW2+mb2 + s1; x = BN(s3)
        gemmM(stream, s1, wt + O_M1 + (long)l * 131072, (const float*)d_in[17] + l * 512, nullptr, big, NN, 256, 512, 1);
        gemmM(stream, big, wt + O_M2 + (long)l * 131072, (const float*)d_in[19] + l * 256, s1, s3, NN, 512, 256, 0);
        run_bn(stream, s3, part, stats, (const float*)d_in[24] + l * 256, (const float*)d_in[25] + l * 256, nullptr, x);
    }

    ln_kernel<<<NN, 256, 0, stream>>>(x, (const float*)d_in[26], (const float*)d_in[27], s1);
    pool_kernel<<<GG, 256, 0, stream>>>(s1, gf);

    // types_pred -> out[0 : N*100]
    gemmM(stream, s1, wt + O_TRO, (const float*)d_in[29], nullptr, s2, NN, 256, 128, 2);
    gemm(stream, s2, (const float*)d_in[30], (const float*)d_in[31], nullptr, out, NN, 128, 100, 0);
    // lattice_pred -> out[N*100 : +G*9]
    gemm(stream, gf,  (const float*)d_in[32], (const float*)d_in[33], nullptr, l1b, GG, 256, 128, 2);
    gemm(stream, l1b, (const float*)d_in[34], (const float*)d_in[35], nullptr, l2b, GG, 128, 64, 2);
    gemm(stream, l2b, (const float*)d_in[36], nullptr, nullptr, out + (size_t)NN * 100, GG, 64, 9, 0);
    // frac_pred -> out[N*100+G*9 : ]
    gemmM(stream, s1, wt + O_FC, (const float*)d_in[38], nullptr, s2, NN, 256, 128, 2);
    gemm(stream, s2, (const float*)d_in[39], (const float*)d_in[40], nullptr, s3, NN, 128, 64, 2);
    gemm(stream, s3, (const float*)d_in[41], nullptr, nullptr, out + (size_t)NN * 100 + GG * 9, NN, 64, 3, 0);
}

// Round 15
// 926.072 us; speedup vs baseline: 12.8609x; 1.0949x over previous
//
#include <hip/hip_runtime.h>
#include <hip/hip_bf16.h>
#include <math.h>

#define GG 256
#define NP 24
#define LL 3
#define CC 256
#define NN (GG*NP)   // 6144 nodes
#define HH 4
#define DH 64

typedef __hip_bfloat16 bf;
typedef __attribute__((ext_vector_type(8))) short bfrag;   // 8 bf16 (4 VGPR)
typedef __attribute__((ext_vector_type(4))) float ffrag;   // 4 fp32 acc

__device__ __forceinline__ short pk(float x) {
    union { bf h; short s; } u; u.h = __float2bfloat16(x); return u.s;
}
__device__ __forceinline__ float b2f_s(short x) {
    union { short s; bf h; } u; u.s = x; return __bfloat162float(u.h);
}

// ---------------------------------------------------------------------------
__global__ void detect_int_k(const unsigned int* __restrict__ at, int* flags) {
    __shared__ int ok;
    if (threadIdx.x == 0) ok = 1;
    __syncthreads();
    if (at[2 * threadIdx.x + 1] != 0u) ok = 0;   // benign race
    __syncthreads();
    if (threadIdx.x == 0) flags[0] = ok;
}

__global__ void signal_k(float* out, int n, float val) {
    int i = blockIdx.x * 256 + threadIdx.x;
    if (i < n) out[i] = val;
}

// ---------------------------------------------------------------------------
// Combined weight prep (9 segments in ONE dispatch): fp32 [L][K][N] ->
// bf16 [L][N][K] at wt+dstOff.
// ---------------------------------------------------------------------------
struct TArgs {
    const float* src[9];
    long dstOff[9];
    int K[9], N[9], L[9];
    int blk0[10];
};
__global__ void transp_all(TArgs a, bf* __restrict__ wt) {
    int bid = blockIdx.x;
    int s = 0;
    while (s < 8 && bid >= a.blk0[s + 1]) ++s;
    long idx = (long)(bid - a.blk0[s]) * 256 + threadIdx.x;
    int KN = a.K[s] * a.N[s];
    long sz = (long)KN * a.L[s];
    if (idx >= sz) return;
    int l = (int)(idx / KN);
    int rem = (int)(idx % KN);
    int k = rem / a.N[s], n = rem % a.N[s];
    wt[a.dstOff[s] + (long)l * KN + (long)n * a.K[s] + k] =
        __float2bfloat16(a.src[s][idx]);
}

// ---------------------------------------------------------------------------
// GINE edge-weight prep: geW fp32 [L][69][256] -> split bf16 W^T
// [L][half][n 0..127][k 0..63] (k<60 real, else 0), hi and lo parts.
// ---------------------------------------------------------------------------
__global__ void prep_gew(const float* __restrict__ geW, short* __restrict__ wh,
                         short* __restrict__ wl) {
    int idx = blockIdx.x * 256 + threadIdx.x;   // 3*2*128*64 = 49152
    if (idx >= 49152) return;
    int k = idx & 63;
    int n = (idx >> 6) & 127;
    int half = (idx >> 13) & 1;
    int l = idx >> 14;
    float v = (k < 60) ? geW[(long)l * 69 * 256 + (long)k * 256 + half * 128 + n] : 0.f;
    short hi = pk(v);
    short lo = pk(v - b2f_s(hi));
    wh[idx] = hi;
    wl[idx] = lo;
}

// ---------------------------------------------------------------------------
// A = [type_emb[atom_types] | time_emb]  (N x 512, fp32)
// ---------------------------------------------------------------------------
__global__ void build_A(const float* __restrict__ t, const float* __restrict__ type_emb,
                        const unsigned int* __restrict__ atoms,
                        float* __restrict__ A, const int* __restrict__ flags) {
    int i64 = flags[0];
    int idx = blockIdx.x * 256 + threadIdx.x;
    if (idx >= NN * 512) return;
    int n = idx >> 9;
    int k = idx & 511;
    if (k < 256) {
        int a = i64 ? (int)atoms[2 * n] : (int)atoms[n];
        A[idx] = type_emb[(long)a * CC + k];
    } else {
        int d = k - 256;
        int g = n / NP;
        float tv = t[g];
        int dd = (d < 128) ? d : d - 128;
        float tf = expf(dd * (-9.210340371976184f / 127.0f));
        float ang = tv * tf;
        A[idx] = (d < 128) ? sinf(ang) : cosf(ang);
    }
}

// ---------------------------------------------------------------------------
// MFMA bf16 GEMM (validated R11). C = epi(A@W + bias) (+res), Wt = bf16 W^T.
// ---------------------------------------------------------------------------
__global__ __launch_bounds__(256) void gemm_mfma(
        const float* __restrict__ A, const bf* __restrict__ Wt,
        const float* __restrict__ bias, const float* __restrict__ res,
        float* __restrict__ C, int M, int K, int N, int act) {
    __shared__ short As[64 * 40];
    __shared__ short Bs[128 * 40];
    int tid = threadIdx.x;
    int lane = tid & 63, w = tid >> 6;
    int wm = w & 1, wn = w >> 1;
    int m0 = blockIdx.x * 64, n0 = blockIdx.y * 128;
    ffrag acc[2][4] = {};
    int sa_m = tid >> 2, sa_k = (tid & 3) << 3;
    int sb_n = tid >> 1, sb_k = (tid & 1) << 4;
    int fr_row = lane & 15, fr_k = (lane >> 4) << 3;

    for (int k0 = 0; k0 < K; k0 += 32) {
        const float* Ap = A + (long)(m0 + sa_m) * K + k0 + sa_k;
        float4 a1 = *(const float4*)Ap;
        float4 a2 = *(const float4*)(Ap + 4);
        const float4* Bp = (const float4*)(Wt + (long)(n0 + sb_n) * K + k0 + sb_k);
        float4 b1 = Bp[0], b2 = Bp[1];
        __syncthreads();
        bfrag av;
        av[0] = pk(a1.x); av[1] = pk(a1.y); av[2] = pk(a1.z); av[3] = pk(a1.w);
        av[4] = pk(a2.x); av[5] = pk(a2.y); av[6] = pk(a2.z); av[7] = pk(a2.w);
        *(bfrag*)(&As[sa_m * 40 + sa_k]) = av;
        *(float4*)(&Bs[sb_n * 40 + sb_k]) = b1;
        *(float4*)(&Bs[sb_n * 40 + sb_k + 8]) = b2;
        __syncthreads();
        bfrag af[2], bg[4];
#pragma unroll
        for (int mt = 0; mt < 2; ++mt)
            af[mt] = *(const bfrag*)(&As[(wm * 32 + mt * 16 + fr_row) * 40 + fr_k]);
#pragma unroll
        for (int nt = 0; nt < 4; ++nt)
            bg[nt] = *(const bfrag*)(&Bs[(wn * 64 + nt * 16 + fr_row) * 40 + fr_k]);
#pragma unroll
        for (int mt = 0; mt < 2; ++mt)
#pragma unroll
            for (int nt = 0; nt < 4; ++nt)
                acc[mt][nt] = __builtin_amdgcn_mfma_f32_16x16x32_bf16(
                    af[mt], bg[nt], acc[mt][nt], 0, 0, 0);
    }

    int mbase = (lane >> 4) << 2;
#pragma unroll
    for (int mt = 0; mt < 2; ++mt) {
#pragma unroll
        for (int nt = 0; nt < 4; ++nt) {
            int n = n0 + wn * 64 + nt * 16 + (lane & 15);
            float bv = bias ? bias[n] : 0.f;
#pragma unroll
            for (int r = 0; r < 4; ++r) {
                int m = m0 + wm * 32 + mt * 16 + mbase + r;
                float v = acc[mt][nt][r] + bv;
                if (act == 1) v = fmaxf(v, 0.f);
                else if (act == 2) v = v / (1.f + expf(-v));
                if (res) v += res[(long)m * N + n];
                C[(long)m * N + n] = v;
            }
        }
    }
}

// ---------------------------------------------------------------------------
// fp32 tiled GEMM (small/odd-N). Validated R9-R13.
// ---------------------------------------------------------------------------
__global__ __launch_bounds__(256) void gemm_k(
        const float* __restrict__ A, const float* __restrict__ W,
        const float* __restrict__ bias, const float* __restrict__ res,
        float* __restrict__ Cf, int M, int K, int Nc, int act) {
    __shared__ __align__(16) float Asf[32][64];
    __shared__ __align__(16) float Bsf[32][64];
    int tid = threadIdx.x;
    int tx = tid & 15, ty = tid >> 4;
    int m0 = blockIdx.x * 64, n0 = blockIdx.y * 64;
    float acc[4][4] = {{0.f}};
    int am = tid >> 2;
    int ak = (tid & 3) << 3;
    int bk = tid >> 4;
    int bn = (tid & 15) << 2;

    for (int k0 = 0; k0 < K; k0 += 32) {
        const float* Ap = A + (long)(m0 + am) * K + k0 + ak;
        float4 a1 = *(const float4*)Ap;
        float4 a2 = *(const float4*)(Ap + 4);
        float w1[4], w2[4];
#pragma unroll
        for (int u = 0; u < 4; ++u) {
            int n = n0 + bn + u;
            w1[u] = (n < Nc) ? W[(long)(k0 + bk) * Nc + n] : 0.f;
            w2[u] = (n < Nc) ? W[(long)(k0 + bk + 16) * Nc + n] : 0.f;
        }
        __syncthreads();
        Asf[ak + 0][am] = a1.x; Asf[ak + 1][am] = a1.y;
        Asf[ak + 2][am] = a1.z; Asf[ak + 3][am] = a1.w;
        Asf[ak + 4][am] = a2.x; Asf[ak + 5][am] = a2.y;
        Asf[ak + 6][am] = a2.z; Asf[ak + 7][am] = a2.w;
#pragma unroll
        for (int u = 0; u < 4; ++u) {
            Bsf[bk][bn + u] = w1[u];
            Bsf[bk + 16][bn + u] = w2[u];
        }
        __syncthreads();
#pragma unroll
        for (int k = 0; k < 32; ++k) {
            float4 a = *(const float4*)(&Asf[k][ty << 2]);
            float4 b = *(const float4*)(&Bsf[k][tx << 2]);
            acc[0][0] += a.x * b.x; acc[0][1] += a.x * b.y; acc[0][2] += a.x * b.z; acc[0][3] += a.x * b.w;
            acc[1][0] += a.y * b.x; acc[1][1] += a.y * b.y; acc[1][2] += a.y * b.z; acc[1][3] += a.y * b.w;
            acc[2][0] += a.z * b.x; acc[2][1] += a.z * b.y; acc[2][2] += a.z * b.z; acc[2][3] += a.z * b.w;
            acc[3][0] += a.w * b.x; acc[3][1] += a.w * b.y; acc[3][2] += a.w * b.z; acc[3][3] += a.w * b.w;
        }
    }
#pragma unroll
    for (int i = 0; i < 4; ++i) {
        int m = m0 + (ty << 2) + i;
#pragma unroll
        for (int j = 0; j < 4; ++j) {
            int n = n0 + (tx << 2) + j;
            if (n >= Nc) continue;
            float v = acc[i][j];
            if (bias) v += bias[n];
            if (act == 1) v = fmaxf(v, 0.f);
            else if (act == 2) v = v / (1.f + expf(-v));
            if (res) v += res[(long)m * Nc + n];
            Cf[(long)m * Nc + n] = v;
        }
    }
}

// ---------------------------------------------------------------------------
// GINE v7 — MFMA split-bf16. Numerics = R13 EXACTLY (libm sinf/cosf restored;
// R14's HW trig shifted absmax 3.540->3.662e-3, over threshold).
// Structural (value-preserving) R14 wins kept:
//  * B fragments direct from global (no Wh/Wl LDS; 22.7 KB -> 4 blocks/CU)
//  * Block = (g, half, j-half): 1024 blocks, 12 j-chunks each.
// Semantics == gine_naive (validated R6).
// ---------------------------------------------------------------------------
__global__ __launch_bounds__(256, 4) void gine4(
        const float* __restrict__ x, const float* __restrict__ frac,
        const float* __restrict__ lattice, const float* __restrict__ geW,
        const float* __restrict__ geb, const short* __restrict__ gewt_h,
        const short* __restrict__ gewt_l, float* __restrict__ z, int l) {
    __shared__ __align__(16) short Eh[32 * 72];    // 4608 B
    __shared__ __align__(16) short El[32 * 72];    // 4608 B
    __shared__ __align__(16) float xls[24 * 132];  // 12672 B
    __shared__ float basel[128];                   // 512 B
    __shared__ float fr[72];                       // 288 B  (total ~22.7 KB)

    int tid = threadIdx.x;
    int lane = tid & 63, w = tid >> 6, quad = lane >> 4, l16 = lane & 15;
    int g = blockIdx.x >> 2;
    int half = (blockIdx.x >> 1) & 1;
    int jh = blockIdx.x & 1;           // j range jh*12 .. jh*12+11

    // ---- stage x half (float4), frac, base ----
    {
        const float4* xg = (const float4*)x;
        for (int idx = tid; idx < 768; idx += 256) {
            int i = idx >> 5, c4 = idx & 31;
            ((float4*)(xls + i * 132))[c4] =
                xg[((long)(g * NP + i) * CC + half * 128) / 4 + c4];
        }
    }
    if (tid < 72) fr[tid] = frac[g * 72 + tid];
    if (tid < 128) {
        int cg = half * 128 + tid;
        float bv = geb[(long)l * CC + cg];
#pragma unroll
        for (int q = 0; q < 9; ++q)
            bv += lattice[(long)g * 9 + q] * geW[(long)l * 69 * 256 + (long)(60 + q) * 256 + cg];
        basel[tid] = bv;
    }
    // pre-zero E pad rows 24..31 (never rewritten)
    for (int idx = tid; idx < 512; idx += 256) {
        int i = 24 + (idx >> 6), k = idx & 63;
        Eh[i * 72 + k] = 0;
        El[i * 72 + k] = 0;
    }

    // ---- B fragments direct from global (loop-invariant) ----
    bfrag bh[2][2], bl[2][2];
    {
        long base = (long)(l * 2 + half) * 8192;   // shorts: 128 rows x 64
#pragma unroll
        for (int nt = 0; nt < 2; ++nt) {
            int nrow = w * 32 + nt * 16 + l16;
#pragma unroll
            for (int ks = 0; ks < 2; ++ks) {
                bh[nt][ks] = *(const bfrag*)(gewt_h + base + nrow * 64 + ks * 32 + quad * 8);
                bl[nt][ks] = *(const bfrag*)(gewt_l + base + nrow * 64 + ks * 32 + quad * 8);
            }
        }
    }
    __syncthreads();
    float bse[2];
#pragma unroll
    for (int nt = 0; nt < 2; ++nt) bse[nt] = basel[w * 32 + nt * 16 + l16];

    // ---- chunk loop over dst j (12 per block) ----
    for (int jc = 0; jc < 12; ++jc) {
        int j = jh * 12 + jc;
        // build E rows 0..23 (1536 items) — libm trig (R13-exact numerics)
        for (int idx = tid; idx < 1536; idx += 256) {
            int i = idx >> 6, k = idx & 63;
            float val = 0.f;
            if (k < 60) {
                int r = (k < 30) ? k : k - 30;
                int d = r / 10, f = r % 10;
                float fd = fr[j * 3 + d] - fr[i * 3 + d];
                fd -= floorf(fd);
                float ang = 6.283185307179586f * (float)f * fd;
                val = (k < 30) ? sinf(ang) : cosf(ang);
            }
            short hi = pk(val);
            Eh[i * 72 + k] = hi;
            El[i * 72 + k] = pk(val - b2f_s(hi));
        }
        __syncthreads();

        ffrag acc[2][2] = {};   // [mt][nt]
#pragma unroll
        for (int mt = 0; mt < 2; ++mt) {
            int row = mt * 16 + l16;
#pragma unroll
            for (int ks = 0; ks < 2; ++ks) {
                bfrag ah = *(const bfrag*)(&Eh[row * 72 + ks * 32 + quad * 8]);
                bfrag al = *(const bfrag*)(&El[row * 72 + ks * 32 + quad * 8]);
#pragma unroll
                for (int nt = 0; nt < 2; ++nt) {
                    acc[mt][nt] = __builtin_amdgcn_mfma_f32_16x16x32_bf16(ah, bh[nt][ks], acc[mt][nt], 0, 0, 0);
                    acc[mt][nt] = __builtin_amdgcn_mfma_f32_16x16x32_bf16(ah, bl[nt][ks], acc[mt][nt], 0, 0, 0);
                    acc[mt][nt] = __builtin_amdgcn_mfma_f32_16x16x32_bf16(al, bh[nt][ks], acc[mt][nt], 0, 0, 0);
                }
            }
        }

        // epilogue: relu + reduce over i, write z[g*24+j][cg]
#pragma unroll
        for (int nt = 0; nt < 2; ++nt) {
            int cl = w * 32 + nt * 16 + l16;
            float part = 0.f;
#pragma unroll
            for (int mt = 0; mt < 2; ++mt) {
                int ibase = mt * 16 + quad * 4;
                if (ibase < 24) {
#pragma unroll
                    for (int r = 0; r < 4; ++r) {
                        float xv = xls[(ibase + r) * 132 + cl];
                        part += fmaxf(xv + bse[nt] + acc[mt][nt][r], 0.f);
                    }
                }
            }
            part += __shfl_xor(part, 16);
            part += __shfl_xor(part, 32);
            if (lane < 16)
                z[(long)(g * NP + j) * CC + half * 128 + cl] = xls[j * 132 + cl] + part;
        }
        __syncthreads();   // protect E before next chunk's writes
    }
}

// ---------------------------------------------------------------------------
__global__ void bn_stats1(const float* __restrict__ in, float* __restrict__ part) {
    int c = threadIdx.x, b = blockIdx.x;
    float s = 0.f, q = 0.f;
    for (int r = 0; r < 64; ++r) {
        float v = in[(long)(b * 64 + r) * CC + c];
        s += v; q += v * v;
    }
    part[b * 512 + c] = s;
    part[b * 512 + 256 + c] = q;
}
__global__ void bn_stats2(const float* __restrict__ part, float* __restrict__ stats) {
    int c = threadIdx.x;
    float s = 0.f, q = 0.f;
    for (int b = 0; b < 96; ++b) { s += part[b * 512 + c]; q += part[b * 512 + 256 + c]; }
    float m = s / (float)NN;
    float var = q / (float)NN - m * m;
    stats[c] = m;
    stats[256 + c] = rsqrtf(var + 1e-5f);
}
__global__ void bn_apply(const float* __restrict__ in, const float* __restrict__ stats,
                         const float* __restrict__ gma, const float* __restrict__ bta,
                         const float* __restrict__ add, float* __restrict__ out) {
    long idx = (long)blockIdx.x * 256 + threadIdx.x;
    int c = (int)(idx & 255);
    float v = (in[idx] - stats[c]) * stats[256 + c] * gma[c] + bta[c];
    if (add) v += add[idx];
    out[idx] = v;
}

// ---------------------------------------------------------------------------
// Attention v2 (validated R10).
// ---------------------------------------------------------------------------
__global__ __launch_bounds__(256, 2) void attn2(const float* __restrict__ qkv,
                                                float* __restrict__ o) {
    __shared__ __align__(16) float Kl[24 * 4 * 68];
    __shared__ __align__(16) float Vl[24 * 4 * 68];
    __shared__ float S[4 * 24 * 25];
    int tid = threadIdx.x, g = blockIdx.x;

    const float4* qkv4 = (const float4*)(qkv + (long)g * NP * 768);
    for (int idx = tid; idx < 24 * 128; idx += 256) {
        int row = idx >> 7;
        int c4 = idx & 127;
        int isV = c4 >> 6;
        int cc = c4 & 63;
        int h = cc >> 4, d4 = cc & 15;
        float4 val = qkv4[row * 192 + 64 + c4];
        float* dst = (isV ? Vl : Kl) + (row * 4 + h) * 68 + d4 * 4;
        *(float4*)dst = val;
    }
    __syncthreads();

    if (tid < 96) {
        int h = tid & 3, i = tid >> 2;
        const float4* qp = (const float4*)(qkv + ((long)(g * NP + i)) * 768 + h * 64);
        float4 q[16];
#pragma unroll
        for (int k = 0; k < 16; ++k) q[k] = qp[k];
        float sc[24];
        float mx = -1e30f;
        for (int j = 0; j < 24; ++j) {
            const float4* kp = (const float4*)(Kl + (j * 4 + h) * 68);
            float da = 0.f, db = 0.f;
#pragma unroll
            for (int k = 0; k < 16; k += 2) {
                float4 kv = kp[k];
                da += q[k].x * kv.x; da += q[k].y * kv.y;
                da += q[k].z * kv.z; da += q[k].w * kv.w;
                float4 kv2 = kp[k + 1];
                db += q[k + 1].x * kv2.x; db += q[k + 1].y * kv2.y;
                db += q[k + 1].z * kv2.z; db += q[k + 1].w * kv2.w;
            }
            float s = (da + db) * 0.125f;
            sc[j] = s;
            mx = fmaxf(mx, s);
        }
        float sum = 0.f;
#pragma unroll
        for (int j = 0; j < 24; ++j) { float p = expf(sc[j] - mx); sc[j] = p; sum += p; }
        float inv = 1.f / sum;
#pragma unroll
        for (int j = 0; j < 24; ++j) S[(h * 24 + i) * 25 + j] = sc[j] * inv;
    }
    __syncthreads();

    int h = tid >> 6, d = tid & 63;
    for (int i = 0; i < 24; ++i) {
        const float* Sp = S + (h * 24 + i) * 25;
        float a0 = 0.f, a1 = 0.f;
#pragma unroll
        for (int j = 0; j < 24; j += 2) {
            a0 += Sp[j] * Vl[(j * 4 + h) * 68 + d];
            a1 += Sp[j + 1] * Vl[((j + 1) * 4 + h) * 68 + d];
        }
        o[(long)(g * NP + i) * CC + h * 64 + d] = a0 + a1;
    }
}

// ---------------------------------------------------------------------------
__global__ __launch_bounds__(256) void ln_kernel(const float* __restrict__ x,
        const float* __restrict__ gma, const float* __restrict__ bta,
        float* __restrict__ out) {
    __shared__ float red[256];
    int n = blockIdx.x, c = threadIdx.x;
    float v = x[(long)n * CC + c];
    red[c] = v;
    __syncthreads();
    for (int s = 128; s > 0; s >>= 1) { if (c < s) red[c] += red[c + s]; __syncthreads(); }
    float m = red[0] * (1.f / 256.f);
    __syncthreads();
    float dv = v - m;
    red[c] = dv * dv;
    __syncthreads();
    for (int s = 128; s > 0; s >>= 1) { if (c < s) red[c] += red[c + s]; __syncthreads(); }
    float var = red[0] * (1.f / 256.f);
    out[(long)n * CC + c] = dv * rsqrtf(var + 1e-5f) * gma[c] + bta[c];
}

__global__ void pool_kernel(const float* __restrict__ hn, float* __restrict__ gf) {
    int g = blockIdx.x, c = threadIdx.x;
    float s = 0.f;
    for (int j = 0; j < NP; ++j) s += hn[(long)(g * NP + j) * CC + c];
    gf[g * CC + c] = s * (1.f / 24.f);
}

// ---------------------------------------------------------------------------
static void gemm(hipStream_t st, const float* A, const float* W, const float* bias,
                 const float* res, float* Cf, int M, int K, int Nc, int act) {
    dim3 grid(M / 64, (Nc + 63) / 64);
    gemm_k<<<grid, 256, 0, st>>>(A, W, bias, res, Cf, M, K, Nc, act);
}

static void gemmM(hipStream_t st, const float* A, const bf* Wt, const float* bias,
                  const float* res, float* Cf, int M, int K, int N, int act) {
    dim3 grid(M / 64, N / 128);
    gemm_mfma<<<grid, 256, 0, st>>>(A, Wt, bias, res, Cf, M, K, N, act);
}

static void run_bn(hipStream_t st, const float* in, float* part, float* stats,
                   const float* g_, const float* b_, const float* add, float* out) {
    bn_stats1<<<96, 256, 0, st>>>(in, part);
    bn_stats2<<<1, 256, 0, st>>>(part, stats);
    bn_apply<<<NN, 256, 0, st>>>(in, stats, g_, b_, add, out);
}

extern "C" void kernel_launch(void* const* d_in, const int* in_sizes, int n_in,
                              void* d_out, int out_size, void* d_ws, size_t ws_size,
                              hipStream_t stream) {
    float* out = (float*)d_out;
    int sigN = out_size < 256 ? out_size : 256;

    static const int EXP_SIZES[46] = {
        256, 18432, 2304, 25600, 131072, 256, 52992, 768, 196608, 768,
        196608, 768, 589824, 2304, 196608, 768, 393216, 1536, 393216, 768,
        768, 768, 768, 768, 768, 768, 256, 256, 32768, 128,
        12800, 100, 32768, 128, 8192, 64, 576, 32768, 128, 8192,
        64, 192, 6144, 6144, 147456, 147456 };
    if (n_in != 46) { signal_k<<<1, 256, 0, stream>>>(out, sigN, 3000.f + 8.f * n_in); return; }
    for (int i = 0; i < 46; ++i)
        if (in_sizes[i] != EXP_SIZES[i]) { signal_k<<<1, 256, 0, stream>>>(out, sigN, 512.f + 8.f * i); return; }
    if (out_size != NN * 100 + GG * 9 + NN * 3) { signal_k<<<1, 256, 0, stream>>>(out, sigN, 7777.f); return; }

    // ---- workspace ----
    char* base = (char*)d_ws;
    int* flags = (int*)base;                       // 256 B
    float* f32a = (float*)(base + 256);
    float* x  = f32a;                              // N*256
    float* s1 = x  + (size_t)NN * 256;             // N*256
    float* s2 = s1 + (size_t)NN * 256;             // N*256
    float* big = s2 + (size_t)NN * 256;            // N*768
    float* s3 = big + (size_t)NN * 512;            // alias of big's tail (lifetimes audited)
    float* part = big + (size_t)NN * 768;          // 96*512
    float* stats = part + 96 * 512;                // 512
    float* gf  = stats + 512;                      // G*256
    float* l1b = gf + GG * 256;                    // G*128
    float* l2b = l1b + GG * 128;                   // G*64
    bf* wt = (bf*)(l2b + GG * 64);                 // bf16 W^T mirrors
    const long O_NA = 0, O_G1 = 131072, O_G2 = 327680, O_AI = 524288,
               O_AO = 1114112, O_M1 = 1310720, O_M2 = 1703936,
               O_TRO = 2097152, O_FC = 2129920, WT_TOT = 2162688;
    short* gewt_h = (short*)(wt + WT_TOT);         // 49152 shorts
    short* gewt_l = gewt_h + 49152;                // 49152 shorts
    size_t REQ = 256 + ((size_t)NN * 1536 + 96 * 512 + 512 + GG * 448) * 4
               + WT_TOT * 2 + 49152 * 2 * 2;
    if (ws_size < REQ) { signal_k<<<1, 256, 0, stream>>>(out, sigN, 9999.f); return; }

    const float* t       = (const float*)d_in[0];
    const float* frac    = (const float*)d_in[1];
    const float* lattice = (const float*)d_in[2];
    const float* type_emb = (const float*)d_in[3];

    detect_int_k<<<1, 256, 0, stream>>>((const unsigned int*)d_in[42], flags);

    // combined weight prep (one dispatch for the 9 transposes)
    {
        TArgs ta;
        const int srcIdx[9] = {4, 8, 10, 12, 14, 16, 18, 28, 37};
        const long dof[9]  = {O_NA, O_G1, O_G2, O_AI, O_AO, O_M1, O_M2, O_TRO, O_FC};
        const int Ks[9] = {512, 256, 256, 256, 256, 256, 512, 256, 256};
        const int Ns[9] = {256, 256, 256, 768, 256, 512, 256, 128, 128};
        const int Ls[9] = {1, 3, 3, 3, 3, 3, 3, 1, 1};
        int blk = 0;
        for (int s = 0; s < 9; ++s) {
            ta.src[s] = (const float*)d_in[srcIdx[s]];
            ta.dstOff[s] = dof[s];
            ta.K[s] = Ks[s]; ta.N[s] = Ns[s]; ta.L[s] = Ls[s];
            ta.blk0[s] = blk;
            blk += (Ks[s] * Ns[s] * Ls[s] + 255) / 256;
        }
        ta.blk0[9] = blk;
        transp_all<<<blk, 256, 0, stream>>>(ta, wt);
    }
    prep_gew<<<192, 256, 0, stream>>>((const float*)d_in[6], gewt_h, gewt_l);

    // x0 = concat(type_emb[atoms], time_emb) @ naW + nab
    build_A<<<(NN * 512 + 255) / 256, 256, 0, stream>>>(t, type_emb,
        (const unsigned int*)d_in[42], big, flags);
    gemmM(stream, big, wt + O_NA, (const float*)d_in[5], nullptr, x, NN, 512, 256, 0);

    for (int l = 0; l < LL; ++l) {
        // GINE: s1 = x + aggr (MFMA split-bf16, libm trig)
        gine4<<<GG * 4, 256, 0, stream>>>(x, frac, lattice,
            (const float*)d_in[6], (const float*)d_in[7], gewt_h, gewt_l, s1, l);
        // s2 = silu(s1@gW1+gb1); s3 = s2@gW2+gb2 + x; h1 = BN(s3) -> s2
        gemmM(stream, s1, wt + O_G1 + (long)l * 65536, (const float*)d_in[9]  + l * 256, nullptr, s2, NN, 256, 256, 2);
        gemmM(stream, s2, wt + O_G2 + (long)l * 65536, (const float*)d_in[11] + l * 256, x, s3, NN, 256, 256, 0);
        run_bn(stream, s3, part, stats, (const float*)d_in[20] + l * 256, (const float*)d_in[21] + l * 256, nullptr, s2);
        // attention: qkv=big; o=s1; s3 = s1@aoW+aob + x; s1 = h1 + BN(s3)
        gemmM(stream, x, wt + O_AI + (long)l * 196608, (const float*)d_in[13] + l * 768, nullptr, big, NN, 256, 768, 0);
        attn2<<<GG, 256, 0, stream>>>(big, s1);
        gemmM(stream, s1, wt + O_AO + (long)l * 65536, (const float*)d_in[15] + l * 256, x, s3, NN, 256, 256, 0);
        run_bn(stream, s3, part, stats, (const float*)d_in[22] + l * 256, (const float*)d_in[23] + l * 256, s2, s1);
        // MLP: big = relu(s1@mW1+mb1); s3 = big@mW2+mb2 + s1; x = BN(s3)
        gemmM(stream, s1, wt + O_M1 + (long)l * 131072, (const float*)d_in[17] + l * 512, nullptr, big, NN, 256, 512, 1);
        gemmM(stream, big, wt + O_M2 + (long)l * 131072, (const float*)d_in[19] + l * 256, s1, s3, NN, 512, 256, 0);
        run_bn(stream, s3, part, stats, (const float*)d_in[24] + l * 256, (const float*)d_in[25] + l * 256, nullptr, x);
    }

    ln_kernel<<<NN, 256, 0, stream>>>(x, (const float*)d_in[26], (const float*)d_in[27], s1);
    pool_kernel<<<GG, 256, 0, stream>>>(s1, gf);

    // types_pred -> out[0 : N*100]
    gemmM(stream, s1, wt + O_TRO, (const float*)d_in[29], nullptr, s2, NN, 256, 128, 2);
    gemm(stream, s2, (const float*)d_in[30], (const float*)d_in[31], nullptr, out, NN, 128, 100, 0);
    // lattice_pred -> out[N*100 : +G*9]
    gemm(stream, gf,  (const float*)d_in[32], (const float*)d_in[33], nullptr, l1b, GG, 256, 128, 2);
    gemm(stream, l1b, (const float*)d_in[34], (const float*)d_in[35], nullptr, l2b, GG, 128, 64, 2);
    gemm(stream, l2b, (const float*)d_in[36], nullptr, nullptr, out + (size_t)NN * 100, GG, 64, 9, 0);
    // frac_pred -> out[N*100+G*9 : ]
    gemmM(stream, s1, wt + O_FC, (const float*)d_in[38], nullptr, s2, NN, 256, 128, 2);
    gemm(stream, s2, (const float*)d_in[39], (const float*)d_in[40], nullptr, s3, NN, 128, 64, 2);
    gemm(stream, s3, (const float*)d_in[41], nullptr, nullptr, out + (size_t)NN * 100 + GG * 9, NN, 64, 3, 0);
}